// Round 2
// baseline (1044.985 us; speedup 1.0000x reference)
//
#include <hip/hip_runtime.h>
#include <hip/hip_bf16.h>

// AutoregressiveRoutingHead: B=65536, L=8, LATENT=256, HID=128, NTOK=5
//  K1: G[tok][j] = emb[tok]@W_ih[j] + b_ih[j] + (j<512 ? b_hh[j] : 0)   (6x768 f32)
//  K2: W_hh (768x256 f32) -> bf16 fragment-linear for mfma_32x32x16 A-frags
//  K3: 1024 blocks x 1024 threads; block owns 64 batch rows.
//      16 waves = 8 gate-col slices x 2 batch halves; acc = 48 f32/thread (no spill).
//      h master fp32 in registers; bf16 copy in LDS (frag-linear, conflict-free).
//      Logits accumulated in LDS, written coalesced once at the end.

typedef __attribute__((ext_vector_type(8)))  __bf16 bf16x8;
typedef __attribute__((ext_vector_type(4)))  __bf16 bf16x4;
typedef __attribute__((ext_vector_type(16))) float  f32x16;

__device__ __forceinline__ float sigm(float x) {
    return __builtin_amdgcn_rcpf(1.f + __expf(-x));
}
__device__ __forceinline__ float tanh_fast(float x) {
    float ax = fabsf(x);
    float u  = __expf(-2.f * ax);
    float t  = (1.f - u) * __builtin_amdgcn_rcpf(1.f + u);
    return copysignf(t, x);
}
__device__ __forceinline__ float f4get(const float4& v, int i) {
    return i == 0 ? v.x : i == 1 ? v.y : i == 2 ? v.z : v.w;
}

// ---------------- K1: gi table ----------------
__global__ void k_gtable(const float* __restrict__ emb, const float* __restrict__ W_ih,
                         const float* __restrict__ b_ih, const float* __restrict__ b_hh,
                         float* __restrict__ G) {
    int tok = blockIdx.x;      // 0..5
    int j   = threadIdx.x;     // 0..767
    const float4* e4 = (const float4*)(emb + tok * 128);
    const float4* w4 = (const float4*)(W_ih + (size_t)j * 128);
    float s = 0.f;
#pragma unroll
    for (int k = 0; k < 32; ++k) {
        float4 a = e4[k], b = w4[k];
        s += a.x * b.x + a.y * b.y + a.z * b.z + a.w * b.w;
    }
    s += b_ih[j];
    if (j < 512) s += b_hh[j];   // fold b_hh into r,z gate pre-activations
    G[tok * 768 + j] = s;
}

// ---------------- K2: W_hh -> bf16 fragment-linear ----------------
// Frag (g,s,kc): A[m][k], m = g*256 + 32*s + (lane&31), k = kc*16 + (lane>>5)*8 + j
__global__ void k_wfrag(const float* __restrict__ Whh, __bf16* __restrict__ Wg) {
    int u = blockIdx.x * 256 + threadIdx.x;   // 0..24575
    int lane = u & 63;
    int kc   = (u >> 6) & 15;
    int s    = (u >> 10) & 7;
    int g    = u >> 13;
    int row  = g * 256 + s * 32 + (lane & 31);
    int k0   = kc * 16 + (lane >> 5) * 8;
    const float* src = Whh + (size_t)row * 256 + k0;
    bf16x8 v;
#pragma unroll
    for (int j = 0; j < 8; ++j) v[j] = (__bf16)src[j];
    *(bf16x8*)(Wg + (size_t)u * 8) = v;
}

// ---------------- K3: main recurrent kernel ----------------
#define LOADA(g_, kc_) (*(const bf16x8*)(Wg + ((((size_t)((g_)*8 + s)) * 16 + (kc_)) * 64 + lane) * 8))
#define LOADB(kc_)     (*(const bf16x8*)&h_lds[half][kc_][lane][0])

__global__ __launch_bounds__(1024, 4) void k_main(
    const float* __restrict__ latent, const int* __restrict__ tgt,
    const float* __restrict__ Gtab, const __bf16* __restrict__ Wg,
    const float* __restrict__ b_hh, const float* __restrict__ Wout,
    const float* __restrict__ bout, float* __restrict__ out) {

    __shared__ __bf16 h_lds[2][16][64][8];   // [half][kc][slot][j] : 32 KB, frag-linear
    __shared__ int    tok_lds[64 * 9];       // padded stride 9
    __shared__ float  bhn_lds[256];          // b_hh[512:768]
    __shared__ float  wout_lds[5 * 260];     // W_out padded stride 260
    __shared__ float  red[16][32][5];        // per-wave logit partials (10 KB)
    __shared__ float  logit_lds[64 * 40];    // accumulated logits (10 KB)

    const int tid  = threadIdx.x;
    const int lane = tid & 63;
    const int w    = tid >> 6;       // wave 0..15
    const int s    = w & 7;          // gate-col slice (cols 32s..32s+31)
    const int half = w >> 3;         // batch half (rows half*32..+31)
    const int hk   = lane >> 5;      // k-half within frag
    const int bn   = lane & 31;      // batch-local within half
    const int row0 = blockIdx.x * 64;

    // ---- stage small tables ----
    if (tid < 512) {
        int b = tid >> 3, t = tid & 7;
        tok_lds[b * 9 + t] = (t == 0) ? 5 : tgt[(size_t)(row0 + b) * 8 + t - 1];
    } else if (tid < 768) {
        bhn_lds[tid - 512] = b_hh[tid];      // b_hh[512 + (tid-512)]
    }
    for (int i = tid; i < 5 * 256; i += 1024) wout_lds[(i >> 8) * 260 + (i & 255)] = Wout[i];
    float bo = (tid < 320) ? bout[tid % 5] : 0.f;

    // ---- init h registers (fp32 master) + bf16 LDS copy ----
    float h[16];
    {
        int grow = row0 + half * 32 + bn;
#pragma unroll
        for (int q = 0; q < 4; ++q) {
            int cb = s * 32 + q * 8 + hk * 4;   // gate-col base
            float4 hv = *(const float4*)(latent + (size_t)grow * 256 + cb);
            h[4 * q + 0] = hv.x; h[4 * q + 1] = hv.y;
            h[4 * q + 2] = hv.z; h[4 * q + 3] = hv.w;
            bf16x4 hb;
            hb[0] = (__bf16)hv.x; hb[1] = (__bf16)hv.y;
            hb[2] = (__bf16)hv.z; hb[3] = (__bf16)hv.w;
            *(bf16x4*)&h_lds[half][2 * s + (q >> 1)][(q & 1) * 32 + bn][4 * hk] = hb;
        }
    }
    __syncthreads();

    for (int t = 0; t < 8; ++t) {
        // ---- MFMA phase: acc_g += Wfrag(g,kc) * hfrag(half,kc) ----
        f32x16 ac0, ac1, ac2;
#pragma unroll
        for (int i = 0; i < 16; ++i) { ac0[i] = 0.f; ac1[i] = 0.f; ac2[i] = 0.f; }
#pragma unroll
        for (int kc = 0; kc < 16; ++kc) {
            bf16x8 a0 = LOADA(0, kc);
            bf16x8 a1 = LOADA(1, kc);
            bf16x8 a2 = LOADA(2, kc);
            bf16x8 bb = LOADB(kc);
            ac0 = __builtin_amdgcn_mfma_f32_32x32x16_bf16(a0, bb, ac0, 0, 0, 0);
            ac1 = __builtin_amdgcn_mfma_f32_32x32x16_bf16(a1, bb, ac1, 0, 0, 0);
            ac2 = __builtin_amdgcn_mfma_f32_32x32x16_bf16(a2, bb, ac2, 0, 0, 0);
        }
        __syncthreads();   // all h_lds reads done block-wide

        // ---- combine: GRU gate update (lane-local) + logit partials ----
        // acc layout: batch col = lane&31, gate-row rr = (reg&3)+8*(reg>>2)+4*hk,
        // gate-col = 32s + rr.
        float p0 = 0.f, p1 = 0.f, p2 = 0.f, p3 = 0.f, p4 = 0.f;
        {
            int tok = tok_lds[(half * 32 + bn) * 9 + t];
            const float* Gt = Gtab + tok * 768;
#pragma unroll
            for (int q = 0; q < 4; ++q) {
                int cb = s * 32 + q * 8 + hk * 4;
                float4 g0 = *(const float4*)(Gt + cb);          // i_r + b_ih + b_hh
                float4 g1 = *(const float4*)(Gt + 256 + cb);    // i_z + b_ih + b_hh
                float4 g2 = *(const float4*)(Gt + 512 + cb);    // i_n + b_ih
                float4 bh = *(const float4*)&bhn_lds[cb];       // b_hh (n gate)
                bf16x4 hb;
#pragma unroll
                for (int i = 0; i < 4; ++i) {
                    int r = 4 * q + i;
                    float ar = ac0[r] + f4get(g0, i);
                    float az = ac1[r] + f4get(g1, i);
                    float hn = ac2[r] + f4get(bh, i);
                    float rg = sigm(ar);
                    float zg = sigm(az);
                    float ng = tanh_fast(f4get(g2, i) + rg * hn);
                    float hv = ng + zg * (h[r] - ng);
                    h[r] = hv;
                    hb[i] = (__bf16)hv;
                }
                *(bf16x4*)&h_lds[half][2 * s + (q >> 1)][(q & 1) * 32 + bn][4 * hk] = hb;
                // logit partials from fp32 h
#pragma unroll
                for (int o = 0; o < 5; ++o) {
                    float4 wv = *(const float4*)&wout_lds[o * 260 + cb];
                    float acc = wv.x * h[4 * q + 0] + wv.y * h[4 * q + 1]
                              + wv.z * h[4 * q + 2] + wv.w * h[4 * q + 3];
                    if (o == 0) p0 += acc; else if (o == 1) p1 += acc;
                    else if (o == 2) p2 += acc; else if (o == 3) p3 += acc; else p4 += acc;
                }
            }
        }
        // cross-hk reduce within wave, write per-wave partial
        {
            float v0 = p0 + __shfl_xor(p0, 32, 64);
            float v1 = p1 + __shfl_xor(p1, 32, 64);
            float v2 = p2 + __shfl_xor(p2, 32, 64);
            float v3 = p3 + __shfl_xor(p3, 32, 64);
            float v4 = p4 + __shfl_xor(p4, 32, 64);
            if (hk == 0) {
                red[w][bn][0] = v0; red[w][bn][1] = v1; red[w][bn][2] = v2;
                red[w][bn][3] = v3; red[w][bn][4] = v4;
            }
        }
        __syncthreads();   // partials visible; also h_lds writes visible for next MFMA

        // ---- final reduce across the 8 s-waves of each half -> logit LDS ----
        if (tid < 320) {
            int b = tid / 5, o = tid - 5 * (tid / 5);
            float sm = bo;
#pragma unroll
            for (int j = 0; j < 8; ++j) sm += red[(b >> 5) * 8 + j][b & 31][o];
            logit_lds[b * 40 + t * 5 + o] = sm;
        }
        // next red writes happen after next step's post-MFMA barrier -> safe.
    }
    __syncthreads();
    // ---- coalesced output dump: 64 rows x (8 t x 5 o) contiguous ----
    for (int i = tid; i < 64 * 40; i += 1024)
        out[(size_t)row0 * 40 + i] = logit_lds[i];
}

extern "C" void kernel_launch(void* const* d_in, const int* in_sizes, int n_in,
                              void* d_out, int out_size, void* d_ws, size_t ws_size,
                              hipStream_t stream) {
    const float* latent = (const float*)d_in[0];
    const int*   tgt    = (const int*)d_in[1];
    const float* emb    = (const float*)d_in[2];
    const float* W_ih   = (const float*)d_in[3];
    const float* W_hh   = (const float*)d_in[4];
    const float* b_ih   = (const float*)d_in[5];
    const float* b_hh   = (const float*)d_in[6];
    const float* W_out  = (const float*)d_in[7];
    const float* b_out  = (const float*)d_in[8];
    float* out = (float*)d_out;

    float*  Gtab = (float*)d_ws;                       // 6*768*4   = 18432 B
    __bf16* Wg   = (__bf16*)((char*)d_ws + 18432);     // 768*256*2 = 393216 B

    k_gtable<<<6, 768, 0, stream>>>(emb, W_ih, b_ih, b_hh, Gtab);
    k_wfrag<<<96, 256, 0, stream>>>(W_hh, Wg);
    k_main<<<1024, 1024, 0, stream>>>(latent, tgt, Gtab, Wg, b_hh, W_out, b_out, out);
}

// Round 3
// 583.329 us; speedup vs baseline: 1.7914x; 1.7914x over previous
//
#include <hip/hip_runtime.h>
#include <hip/hip_bf16.h>

// AutoregressiveRoutingHead: B=65536, L=8, LATENT=256, HID=128, NTOK=5
//  K1: G[tok][j] = emb[tok]@W_ih[j] + b_ih[j] + (j<512 ? b_hh[j] : 0)   (6x768 f32)
//  K2: W_hh (768x256 f32) -> bf16 fragment-linear for mfma_32x32x16 A-frags
//  K3: 1024 blocks x 512 threads (8 waves = 2/SIMD -> 256-reg cap, no spill).
//      Block owns 64 batch rows. Wave w owns gate rows {g*256+32w..+32} for
//      g in {r,z,n} -> (r,z,n) triples lane-local -> in-register GRU update.
//      h master fp32 in registers; bf16 copy in LDS (frag-linear, conflict-free).
//      Gtab staged in LDS (padded rows); logits accumulated in LDS, one
//      coalesced dump at the end.

typedef __attribute__((ext_vector_type(8)))  __bf16 bf16x8;
typedef __attribute__((ext_vector_type(4)))  __bf16 bf16x4;
typedef __attribute__((ext_vector_type(16))) float  f32x16;

__device__ __forceinline__ float sigm(float x) {
    return __builtin_amdgcn_rcpf(1.f + __expf(-x));
}
__device__ __forceinline__ float tanh_fast(float x) {
    float ax = fabsf(x);
    float u  = __expf(-2.f * ax);
    float t  = (1.f - u) * __builtin_amdgcn_rcpf(1.f + u);
    return copysignf(t, x);
}
__device__ __forceinline__ float f4get(const float4& v, int i) {
    return i == 0 ? v.x : i == 1 ? v.y : i == 2 ? v.z : v.w;
}

// ---------------- K1: gi table ----------------
__global__ void k_gtable(const float* __restrict__ emb, const float* __restrict__ W_ih,
                         const float* __restrict__ b_ih, const float* __restrict__ b_hh,
                         float* __restrict__ G) {
    int tok = blockIdx.x;      // 0..5
    int j   = threadIdx.x;     // 0..767
    const float4* e4 = (const float4*)(emb + tok * 128);
    const float4* w4 = (const float4*)(W_ih + (size_t)j * 128);
    float s = 0.f;
#pragma unroll
    for (int k = 0; k < 32; ++k) {
        float4 a = e4[k], b = w4[k];
        s += a.x * b.x + a.y * b.y + a.z * b.z + a.w * b.w;
    }
    s += b_ih[j];
    if (j < 512) s += b_hh[j];   // fold b_hh into r,z gate pre-activations
    G[tok * 768 + j] = s;
}

// ---------------- K2: W_hh -> bf16 fragment-linear ----------------
// Frag (g,w,kc): A[m][k], m = g*256 + 32*w + (lane&31), k = kc*16 + (lane>>5)*8 + j
__global__ void k_wfrag(const float* __restrict__ Whh, __bf16* __restrict__ Wg) {
    int u = blockIdx.x * 256 + threadIdx.x;   // 0..24575
    int lane = u & 63;
    int kc   = (u >> 6) & 15;
    int w    = (u >> 10) & 7;
    int g    = u >> 13;
    int row  = g * 256 + w * 32 + (lane & 31);
    int k0   = kc * 16 + (lane >> 5) * 8;
    const float* src = Whh + (size_t)row * 256 + k0;
    bf16x8 v;
#pragma unroll
    for (int j = 0; j < 8; ++j) v[j] = (__bf16)src[j];
    *(bf16x8*)(Wg + (size_t)u * 8) = v;
}

// ---------------- K3: main recurrent kernel ----------------
__global__ __launch_bounds__(512, 2) void k_main(
    const float* __restrict__ latent, const int* __restrict__ tgt,
    const float* __restrict__ Gtab, const __bf16* __restrict__ Wg,
    const float* __restrict__ b_hh, const float* __restrict__ Wout,
    const float* __restrict__ bout, float* __restrict__ out) {

    __shared__ __bf16 h_lds[2][16][64][8];   // [nt][kc][slot][j] : 32 KB, frag-linear
    __shared__ int    tok_lds[64 * 9];       // padded stride 9
    __shared__ float  gtab_lds[6 * 772];     // Gtab, rows padded +4 (bank spread)
    __shared__ float  bhn_lds[256];          // b_hh[512:768]
    __shared__ float  wout_lds[5 * 260];     // W_out padded stride 260
    __shared__ float  red[8][64][5];         // per-wave logit partials (10 KB)
    __shared__ float  logit_lds[64 * 40];    // accumulated logits (10 KB)

    const int tid  = threadIdx.x;
    const int lane = tid & 63;
    const int w    = tid >> 6;       // wave 0..7 : gate-col slice (cols 32w..+31)
    const int hk   = lane >> 5;      // k-half within frag
    const int bn   = lane & 31;      // batch index within nt-half
    const int row0 = blockIdx.x * 64;

    // per-thread A-frag base: frag(g,kc) at wa + g*65536 + kc*512 (elements)
    const __bf16* wa = Wg + (size_t)w * 8192 + (size_t)lane * 8;

    // ---- stage small tables ----
    {
        int b = tid >> 3, t = tid & 7;
        tok_lds[b * 9 + t] = (t == 0) ? 5 : tgt[(size_t)(row0 + b) * 8 + t - 1];
    }
    if (tid < 256) bhn_lds[tid] = b_hh[512 + tid];
    for (int i = tid; i < 5 * 256; i += 512) wout_lds[(i >> 8) * 260 + (i & 255)] = Wout[i];
#pragma unroll
    for (int tok = 0; tok < 6; ++tok)
        for (int i = tid; i < 768; i += 512) gtab_lds[tok * 772 + i] = Gtab[tok * 768 + i];
    float bo = (tid < 320) ? bout[tid % 5] : 0.f;

    // ---- init h registers (fp32 master) + bf16 LDS copy ----
    float h[2][16];
#pragma unroll
    for (int nt = 0; nt < 2; ++nt) {
        int grow = row0 + nt * 32 + bn;
#pragma unroll
        for (int q = 0; q < 4; ++q) {
            int cb = w * 32 + q * 8 + hk * 4;   // gate-col base
            float4 hv = *(const float4*)(latent + (size_t)grow * 256 + cb);
            h[nt][4 * q + 0] = hv.x; h[nt][4 * q + 1] = hv.y;
            h[nt][4 * q + 2] = hv.z; h[nt][4 * q + 3] = hv.w;
            bf16x4 hb;
            hb[0] = (__bf16)hv.x; hb[1] = (__bf16)hv.y;
            hb[2] = (__bf16)hv.z; hb[3] = (__bf16)hv.w;
            *(bf16x4*)&h_lds[nt][2 * w + (q >> 1)][(q & 1) * 32 + bn][4 * hk] = hb;
        }
    }
    __syncthreads();

    for (int t = 0; t < 8; ++t) {
        // ---- MFMA phase: acc[g][nt] += Wfrag(g,kc) * hfrag(nt,kc) ----
        f32x16 acc[3][2];
        {
            f32x16 zz;
#pragma unroll
            for (int i = 0; i < 16; ++i) zz[i] = 0.f;
#pragma unroll
            for (int g = 0; g < 3; ++g)
#pragma unroll
                for (int nt = 0; nt < 2; ++nt) acc[g][nt] = zz;
        }
#pragma unroll
        for (int kc = 0; kc < 16; ++kc) {
            bf16x8 a0 = *(const bf16x8*)(wa + kc * 512);
            bf16x8 a1 = *(const bf16x8*)(wa + 65536 + kc * 512);
            bf16x8 a2 = *(const bf16x8*)(wa + 131072 + kc * 512);
            bf16x8 b0 = *(const bf16x8*)&h_lds[0][kc][lane][0];
            bf16x8 b1 = *(const bf16x8*)&h_lds[1][kc][lane][0];
            acc[0][0] = __builtin_amdgcn_mfma_f32_32x32x16_bf16(a0, b0, acc[0][0], 0, 0, 0);
            acc[0][1] = __builtin_amdgcn_mfma_f32_32x32x16_bf16(a0, b1, acc[0][1], 0, 0, 0);
            acc[1][0] = __builtin_amdgcn_mfma_f32_32x32x16_bf16(a1, b0, acc[1][0], 0, 0, 0);
            acc[1][1] = __builtin_amdgcn_mfma_f32_32x32x16_bf16(a1, b1, acc[1][1], 0, 0, 0);
            acc[2][0] = __builtin_amdgcn_mfma_f32_32x32x16_bf16(a2, b0, acc[2][0], 0, 0, 0);
            acc[2][1] = __builtin_amdgcn_mfma_f32_32x32x16_bf16(a2, b1, acc[2][1], 0, 0, 0);
        }
        __syncthreads();   // all h_lds reads done block-wide

        // ---- combine: GRU gate update (lane-local) + logit partials ----
        // acc layout: batch col = lane&31, gate-row rr = (reg&3)+8*(reg>>2)+4*hk,
        // gate-col = 32w + rr.
        float p[2][5];
#pragma unroll
        for (int nt = 0; nt < 2; ++nt)
#pragma unroll
            for (int o = 0; o < 5; ++o) p[nt][o] = 0.f;
#pragma unroll
        for (int nt = 0; nt < 2; ++nt) {
            int tok = tok_lds[(nt * 32 + bn) * 9 + t];
            const float* Gt = gtab_lds + tok * 772;
#pragma unroll
            for (int q = 0; q < 4; ++q) {
                int cb = w * 32 + q * 8 + hk * 4;
                float4 g0 = *(const float4*)(Gt + cb);          // i_r + b_ih + b_hh
                float4 g1 = *(const float4*)(Gt + 256 + cb);    // i_z + b_ih + b_hh
                float4 g2 = *(const float4*)(Gt + 512 + cb);    // i_n + b_ih
                float4 bh = *(const float4*)&bhn_lds[cb];       // b_hh (n gate)
                bf16x4 hb;
#pragma unroll
                for (int i = 0; i < 4; ++i) {
                    int r = 4 * q + i;
                    float ar = acc[0][nt][r] + f4get(g0, i);
                    float az = acc[1][nt][r] + f4get(g1, i);
                    float hn = acc[2][nt][r] + f4get(bh, i);
                    float rg = sigm(ar);
                    float zg = sigm(az);
                    float ng = tanh_fast(f4get(g2, i) + rg * hn);
                    float hv = ng + zg * (h[nt][r] - ng);
                    h[nt][r] = hv;
                    hb[i] = (__bf16)hv;
                }
                *(bf16x4*)&h_lds[nt][2 * w + (q >> 1)][(q & 1) * 32 + bn][4 * hk] = hb;
                // logit partials from fp32 h
#pragma unroll
                for (int o = 0; o < 5; ++o) {
                    float4 wv = *(const float4*)&wout_lds[o * 260 + cb];
                    p[nt][o] += wv.x * h[nt][4 * q + 0] + wv.y * h[nt][4 * q + 1]
                              + wv.z * h[nt][4 * q + 2] + wv.w * h[nt][4 * q + 3];
                }
            }
        }
        // cross-hk reduce within wave, write per-wave partials
#pragma unroll
        for (int nt = 0; nt < 2; ++nt)
#pragma unroll
            for (int o = 0; o < 5; ++o) {
                float v = p[nt][o] + __shfl_xor(p[nt][o], 32, 64);
                if (hk == 0) red[w][nt * 32 + bn][o] = v;
            }
        __syncthreads();   // partials + h_lds writes visible

        // ---- final reduce across the 8 waves -> logit LDS ----
        if (tid < 320) {
            int b = tid / 5, o = tid - 5 * (tid / 5);
            float sm = bo;
#pragma unroll
            for (int j = 0; j < 8; ++j) sm += red[j][b][o];
            logit_lds[b * 40 + t * 5 + o] = sm;
        }
        // next step's red writes occur after next post-MFMA barrier -> safe.
    }
    __syncthreads();
    // ---- coalesced output dump: 64 rows x (8 t x 5 o) contiguous ----
    for (int i = tid; i < 64 * 40; i += 512)
        out[(size_t)row0 * 40 + i] = logit_lds[i];
}

extern "C" void kernel_launch(void* const* d_in, const int* in_sizes, int n_in,
                              void* d_out, int out_size, void* d_ws, size_t ws_size,
                              hipStream_t stream) {
    const float* latent = (const float*)d_in[0];
    const int*   tgt    = (const int*)d_in[1];
    const float* emb    = (const float*)d_in[2];
    const float* W_ih   = (const float*)d_in[3];
    const float* W_hh   = (const float*)d_in[4];
    const float* b_ih   = (const float*)d_in[5];
    const float* b_hh   = (const float*)d_in[6];
    const float* W_out  = (const float*)d_in[7];
    const float* b_out  = (const float*)d_in[8];
    float* out = (float*)d_out;

    float*  Gtab = (float*)d_ws;                       // 6*768*4   = 18432 B
    __bf16* Wg   = (__bf16*)((char*)d_ws + 18432);     // 768*256*2 = 393216 B

    k_gtable<<<6, 768, 0, stream>>>(emb, W_ih, b_ih, b_hh, Gtab);
    k_wfrag<<<96, 256, 0, stream>>>(W_hh, Wg);
    k_main<<<1024, 512, 0, stream>>>(latent, tgt, Gtab, Wg, b_hh, W_out, b_out, out);
}

// Round 4
// 353.216 us; speedup vs baseline: 2.9585x; 1.6515x over previous
//
#include <hip/hip_runtime.h>
#include <hip/hip_bf16.h>

// AutoregressiveRoutingHead: B=65536, L=8, LATENT=256, HID=128, NTOK=5
//  K1: G[tok][j] = emb[tok]@W_ih[j] + b_ih[j] + (j<512 ? b_hh[j] : 0)   (6x768 f32)
//  K2: W_hh (768x256 f32) -> bf16 fragment-linear for mfma_32x32x16 A-frags
//  K3: 1024 blocks x 512 threads (8 waves, 1 block/CU, 256-reg budget).
//      Wave w owns gate rows {g*256+32w..+32}, g in {r,z,n} -> (r,z,n) triples
//      lane-local -> in-register GRU update. h state lives ONLY in LDS as bf16
//      (no fp32 master: -32 regs). kc-loop unrolled x4 only, to cap in-flight
//      A/B fragments (~50 regs) and avoid the spill seen in r1/r3.
//      Logits accumulated in LDS, one coalesced dump at the end.

typedef __attribute__((ext_vector_type(8)))  __bf16 bf16x8;
typedef __attribute__((ext_vector_type(4)))  __bf16 bf16x4;
typedef __attribute__((ext_vector_type(16))) float  f32x16;

__device__ __forceinline__ float sigm(float x) {
    return __builtin_amdgcn_rcpf(1.f + __expf(-x));
}
__device__ __forceinline__ float tanh_fast(float x) {
    float ax = fabsf(x);
    float u  = __expf(-2.f * ax);
    float t  = (1.f - u) * __builtin_amdgcn_rcpf(1.f + u);
    return copysignf(t, x);
}
__device__ __forceinline__ float f4get(const float4& v, int i) {
    return i == 0 ? v.x : i == 1 ? v.y : i == 2 ? v.z : v.w;
}

// ---------------- K1: gi table ----------------
__global__ void k_gtable(const float* __restrict__ emb, const float* __restrict__ W_ih,
                         const float* __restrict__ b_ih, const float* __restrict__ b_hh,
                         float* __restrict__ G) {
    int tok = blockIdx.x;      // 0..5
    int j   = threadIdx.x;     // 0..767
    const float4* e4 = (const float4*)(emb + tok * 128);
    const float4* w4 = (const float4*)(W_ih + (size_t)j * 128);
    float s = 0.f;
#pragma unroll
    for (int k = 0; k < 32; ++k) {
        float4 a = e4[k], b = w4[k];
        s += a.x * b.x + a.y * b.y + a.z * b.z + a.w * b.w;
    }
    s += b_ih[j];
    if (j < 512) s += b_hh[j];   // fold b_hh into r,z gate pre-activations
    G[tok * 768 + j] = s;
}

// ---------------- K2: W_hh -> bf16 fragment-linear ----------------
// Frag (g,w,kc): A[m][k], m = g*256 + 32*w + (lane&31), k = kc*16 + (lane>>5)*8 + j
__global__ void k_wfrag(const float* __restrict__ Whh, __bf16* __restrict__ Wg) {
    int u = blockIdx.x * 256 + threadIdx.x;   // 0..24575
    int lane = u & 63;
    int kc   = (u >> 6) & 15;
    int w    = (u >> 10) & 7;
    int g    = u >> 13;
    int row  = g * 256 + w * 32 + (lane & 31);
    int k0   = kc * 16 + (lane >> 5) * 8;
    const float* src = Whh + (size_t)row * 256 + k0;
    bf16x8 v;
#pragma unroll
    for (int j = 0; j < 8; ++j) v[j] = (__bf16)src[j];
    *(bf16x8*)(Wg + (size_t)u * 8) = v;
}

// ---------------- K3: main recurrent kernel ----------------
__global__ __launch_bounds__(512, 2) void k_main(
    const float* __restrict__ latent, const int* __restrict__ tgt,
    const float* __restrict__ Gtab, const __bf16* __restrict__ Wg,
    const float* __restrict__ b_hh, const float* __restrict__ Wout,
    const float* __restrict__ bout, float* __restrict__ out) {

    __shared__ __bf16 h_lds[2][16][64][8];   // [nt][kc][slot][j] : 32 KB, frag-linear
    __shared__ int    tok_lds[64 * 9];       // padded stride 9
    __shared__ float  gtab_lds[6 * 772];     // Gtab, rows padded +4 (bank spread)
    __shared__ float  bhn_lds[256];          // b_hh[512:768]
    __shared__ float  wout_lds[5 * 260];     // W_out padded stride 260
    __shared__ float  red[8][64][5];         // per-wave logit partials (10 KB)
    __shared__ float  logit_lds[64 * 40];    // accumulated logits (10 KB)

    const int tid  = threadIdx.x;
    const int lane = tid & 63;
    const int w    = tid >> 6;       // wave 0..7 : gate-col slice (cols 32w..+31)
    const int hk   = lane >> 5;      // k-half within frag
    const int bn   = lane & 31;      // batch index within nt-half
    const int row0 = blockIdx.x * 64;

    // per-thread A-frag base: frag(g,kc) at wa + g*65536 + kc*512 (elements)
    const __bf16* wa = Wg + (size_t)w * 8192 + (size_t)lane * 8;

    // ---- stage small tables ----
    {
        int b = tid >> 3, t = tid & 7;
        tok_lds[b * 9 + t] = (t == 0) ? 5 : tgt[(size_t)(row0 + b) * 8 + t - 1];
    }
    if (tid < 256) bhn_lds[tid] = b_hh[512 + tid];
    for (int i = tid; i < 5 * 256; i += 512) wout_lds[(i >> 8) * 260 + (i & 255)] = Wout[i];
#pragma unroll
    for (int tok = 0; tok < 6; ++tok)
        for (int i = tid; i < 768; i += 512) gtab_lds[tok * 772 + i] = Gtab[tok * 768 + i];
    float bo = (tid < 320) ? bout[tid % 5] : 0.f;

    // ---- init h in LDS (bf16) ----
#pragma unroll
    for (int nt = 0; nt < 2; ++nt) {
        int grow = row0 + nt * 32 + bn;
#pragma unroll
        for (int q = 0; q < 4; ++q) {
            int cb = w * 32 + q * 8 + hk * 4;   // gate-col base
            float4 hv = *(const float4*)(latent + (size_t)grow * 256 + cb);
            bf16x4 hb;
            hb[0] = (__bf16)hv.x; hb[1] = (__bf16)hv.y;
            hb[2] = (__bf16)hv.z; hb[3] = (__bf16)hv.w;
            *(bf16x4*)&h_lds[nt][2 * w + (q >> 1)][(q & 1) * 32 + bn][4 * hk] = hb;
        }
    }
    __syncthreads();

    for (int t = 0; t < 8; ++t) {
        // ---- MFMA phase: acc[g][nt] += Wfrag(g,kc) * hfrag(nt,kc) ----
        f32x16 acc[3][2];
        {
            f32x16 zz;
#pragma unroll
            for (int i = 0; i < 16; ++i) zz[i] = 0.f;
#pragma unroll
            for (int g = 0; g < 3; ++g)
#pragma unroll
                for (int nt = 0; nt < 2; ++nt) acc[g][nt] = zz;
        }
        // unroll 4 ONLY: caps in-flight A/B fragments so regalloc stays spill-free
#pragma unroll 4
        for (int kc = 0; kc < 16; ++kc) {
            bf16x8 a0 = *(const bf16x8*)(wa + kc * 512);
            bf16x8 a1 = *(const bf16x8*)(wa + 65536 + kc * 512);
            bf16x8 a2 = *(const bf16x8*)(wa + 131072 + kc * 512);
            bf16x8 b0 = *(const bf16x8*)&h_lds[0][kc][lane][0];
            bf16x8 b1 = *(const bf16x8*)&h_lds[1][kc][lane][0];
            acc[0][0] = __builtin_amdgcn_mfma_f32_32x32x16_bf16(a0, b0, acc[0][0], 0, 0, 0);
            acc[0][1] = __builtin_amdgcn_mfma_f32_32x32x16_bf16(a0, b1, acc[0][1], 0, 0, 0);
            acc[1][0] = __builtin_amdgcn_mfma_f32_32x32x16_bf16(a1, b0, acc[1][0], 0, 0, 0);
            acc[1][1] = __builtin_amdgcn_mfma_f32_32x32x16_bf16(a1, b1, acc[1][1], 0, 0, 0);
            acc[2][0] = __builtin_amdgcn_mfma_f32_32x32x16_bf16(a2, b0, acc[2][0], 0, 0, 0);
            acc[2][1] = __builtin_amdgcn_mfma_f32_32x32x16_bf16(a2, b1, acc[2][1], 0, 0, 0);
        }
        __syncthreads();   // all h_lds reads done block-wide

        // ---- combine: GRU gate update (lane-local, h_old from LDS) ----
        // acc layout: batch col = lane&31, gate-row rr = (reg&3)+8*(reg>>2)+4*hk,
        // gate-col = 32w + rr.
        float p[2][5];
#pragma unroll
        for (int nt = 0; nt < 2; ++nt)
#pragma unroll
            for (int o = 0; o < 5; ++o) p[nt][o] = 0.f;
#pragma unroll
        for (int nt = 0; nt < 2; ++nt) {
            int tok = tok_lds[(nt * 32 + bn) * 9 + t];
            const float* Gt = gtab_lds + tok * 772;
#pragma unroll
            for (int q = 0; q < 4; ++q) {
                int cb = w * 32 + q * 8 + hk * 4;
                float4 g0 = *(const float4*)(Gt + cb);          // i_r + b_ih + b_hh
                float4 g1 = *(const float4*)(Gt + 256 + cb);    // i_z + b_ih + b_hh
                float4 g2 = *(const float4*)(Gt + 512 + cb);    // i_n + b_ih
                float4 bh = *(const float4*)&bhn_lds[cb];       // b_hh (n gate)
                bf16x4* hslot = (bf16x4*)&h_lds[nt][2 * w + (q >> 1)][(q & 1) * 32 + bn][4 * hk];
                bf16x4 hold = *hslot;                           // h_{t-1}, bf16
                bf16x4 hb;
                float hv[4];
#pragma unroll
                for (int i = 0; i < 4; ++i) {
                    int r = 4 * q + i;
                    float ar = acc[0][nt][r] + f4get(g0, i);
                    float az = acc[1][nt][r] + f4get(g1, i);
                    float hn = acc[2][nt][r] + f4get(bh, i);
                    float rg = sigm(ar);
                    float zg = sigm(az);
                    float ng = tanh_fast(f4get(g2, i) + rg * hn);
                    float hvv = ng + zg * ((float)hold[i] - ng);
                    hv[i] = hvv;
                    hb[i] = (__bf16)hvv;
                }
                *hslot = hb;
                // logit partials from fp32 h values
#pragma unroll
                for (int o = 0; o < 5; ++o) {
                    float4 wv = *(const float4*)&wout_lds[o * 260 + cb];
                    p[nt][o] += wv.x * hv[0] + wv.y * hv[1] + wv.z * hv[2] + wv.w * hv[3];
                }
            }
        }
        // cross-hk reduce within wave, write per-wave partials
#pragma unroll
        for (int nt = 0; nt < 2; ++nt)
#pragma unroll
            for (int o = 0; o < 5; ++o) {
                float v = p[nt][o] + __shfl_xor(p[nt][o], 32, 64);
                if (hk == 0) red[w][nt * 32 + bn][o] = v;
            }
        __syncthreads();   // partials + h_lds writes visible

        // ---- final reduce across the 8 waves -> logit LDS ----
        if (tid < 320) {
            int b = tid / 5, o = tid - 5 * (tid / 5);
            float sm = bo;
#pragma unroll
            for (int j = 0; j < 8; ++j) sm += red[j][b][o];
            logit_lds[b * 40 + t * 5 + o] = sm;
        }
        // next step's red writes occur after next post-MFMA barrier -> safe.
    }
    __syncthreads();
    // ---- coalesced output dump: 64 rows x (8 t x 5 o) contiguous ----
    for (int i = tid; i < 64 * 40; i += 512)
        out[(size_t)row0 * 40 + i] = logit_lds[i];
}

extern "C" void kernel_launch(void* const* d_in, const int* in_sizes, int n_in,
                              void* d_out, int out_size, void* d_ws, size_t ws_size,
                              hipStream_t stream) {
    const float* latent = (const float*)d_in[0];
    const int*   tgt    = (const int*)d_in[1];
    const float* emb    = (const float*)d_in[2];
    const float* W_ih   = (const float*)d_in[3];
    const float* W_hh   = (const float*)d_in[4];
    const float* b_ih   = (const float*)d_in[5];
    const float* b_hh   = (const float*)d_in[6];
    const float* W_out  = (const float*)d_in[7];
    const float* b_out  = (const float*)d_in[8];
    float* out = (float*)d_out;

    float*  Gtab = (float*)d_ws;                       // 6*768*4   = 18432 B
    __bf16* Wg   = (__bf16*)((char*)d_ws + 18432);     // 768*256*2 = 393216 B

    k_gtable<<<6, 768, 0, stream>>>(emb, W_ih, b_ih, b_hh, Gtab);
    k_wfrag<<<96, 256, 0, stream>>>(W_hh, Wg);
    k_main<<<1024, 512, 0, stream>>>(latent, tgt, Gtab, Wg, b_hh, W_out, b_out, out);
}

// Round 5
// 335.991 us; speedup vs baseline: 3.1102x; 1.0513x over previous
//
#include <hip/hip_runtime.h>
#include <hip/hip_bf16.h>

// AutoregressiveRoutingHead: B=65536, L=8, LATENT=256, HID=128, NTOK=5
//  K1: G[tok][j] = emb[tok]@W_ih[j] + b_ih[j] + (j<512 ? b_hh[j] : 0)   (6x768 f32)
//  K2: W_hh (768x256 f32) -> bf16 fragment-linear for mfma_32x32x16 A-frags
//  K3: 1024 blocks x 512 threads (8 waves, 2/SIMD, 256-reg budget, no spill).
//      Wave w owns gate rows {g*256+32w..+32}, g in {r,z,n} -> (r,z,n) triples
//      lane-local -> in-register GRU update. h state bf16 in LDS, DOUBLE
//      BUFFERED: step t reads h_lds[t&1], writes h_lds[~t&1] -> the mid-step
//      barrier is gone and the 2 waves/SIMD desynchronize, overlapping one
//      wave's combine (VALU/trans) with the other's MFMA+L2 stream (m114).
//      One barrier/step. red[] double-buffered so the logit reduce tail is
//      race-free. Logits accumulated in LDS, coalesced dump at the end.

typedef __attribute__((ext_vector_type(8)))  __bf16 bf16x8;
typedef __attribute__((ext_vector_type(4)))  __bf16 bf16x4;
typedef __attribute__((ext_vector_type(16))) float  f32x16;

__device__ __forceinline__ float sigm(float x) {
    return __builtin_amdgcn_rcpf(1.f + __expf(-x));
}
__device__ __forceinline__ float tanh_fast(float x) {
    float ax = fabsf(x);
    float u  = __expf(-2.f * ax);
    float t  = (1.f - u) * __builtin_amdgcn_rcpf(1.f + u);
    return copysignf(t, x);
}
__device__ __forceinline__ float f4get(const float4& v, int i) {
    return i == 0 ? v.x : i == 1 ? v.y : i == 2 ? v.z : v.w;
}

// ---------------- K1: gi table ----------------
__global__ void k_gtable(const float* __restrict__ emb, const float* __restrict__ W_ih,
                         const float* __restrict__ b_ih, const float* __restrict__ b_hh,
                         float* __restrict__ G) {
    int tok = blockIdx.x;      // 0..5
    int j   = threadIdx.x;     // 0..767
    const float4* e4 = (const float4*)(emb + tok * 128);
    const float4* w4 = (const float4*)(W_ih + (size_t)j * 128);
    float s = 0.f;
#pragma unroll
    for (int k = 0; k < 32; ++k) {
        float4 a = e4[k], b = w4[k];
        s += a.x * b.x + a.y * b.y + a.z * b.z + a.w * b.w;
    }
    s += b_ih[j];
    if (j < 512) s += b_hh[j];   // fold b_hh into r,z gate pre-activations
    G[tok * 768 + j] = s;
}

// ---------------- K2: W_hh -> bf16 fragment-linear ----------------
// Frag (g,w,kc): A[m][k], m = g*256 + 32*w + (lane&31), k = kc*16 + (lane>>5)*8 + j
__global__ void k_wfrag(const float* __restrict__ Whh, __bf16* __restrict__ Wg) {
    int u = blockIdx.x * 256 + threadIdx.x;   // 0..24575
    int lane = u & 63;
    int kc   = (u >> 6) & 15;
    int w    = (u >> 10) & 7;
    int g    = u >> 13;
    int row  = g * 256 + w * 32 + (lane & 31);
    int k0   = kc * 16 + (lane >> 5) * 8;
    const float* src = Whh + (size_t)row * 256 + k0;
    bf16x8 v;
#pragma unroll
    for (int j = 0; j < 8; ++j) v[j] = (__bf16)src[j];
    *(bf16x8*)(Wg + (size_t)u * 8) = v;
}

// ---------------- K3: main recurrent kernel ----------------
__global__ __launch_bounds__(512, 2) void k_main(
    const float* __restrict__ latent, const int* __restrict__ tgt,
    const float* __restrict__ Gtab, const __bf16* __restrict__ Wg,
    const float* __restrict__ b_hh, const float* __restrict__ Wout,
    const float* __restrict__ bout, float* __restrict__ out) {

    __shared__ __bf16 h_lds[2][2][16][64][8]; // [buf][nt][kc][slot][j] : 64 KB
    __shared__ int    tok_lds[64 * 9];        // padded stride 9
    __shared__ float  gtab_lds[6 * 772];      // Gtab, rows padded +4
    __shared__ float  bhn_lds[256];           // b_hh[512:768]
    __shared__ float  wout_lds[5 * 260];      // W_out padded stride 260
    __shared__ float  red[2][8][64][5];       // per-wave logit partials, dbuf (20 KB)
    __shared__ float  logit_lds[64 * 40];     // accumulated logits (10 KB)

    const int tid  = threadIdx.x;
    const int lane = tid & 63;
    const int w    = tid >> 6;       // wave 0..7 : gate-col slice (cols 32w..+31)
    const int hk   = lane >> 5;      // k-half within frag
    const int bn   = lane & 31;      // batch index within nt-half
    const int row0 = blockIdx.x * 64;

    // per-thread A-frag base: frag(g,kc) at wa + g*65536 + kc*512 (elements)
    const __bf16* wa = Wg + (size_t)w * 8192 + (size_t)lane * 8;

    // ---- stage small tables ----
    {
        int b = tid >> 3, t = tid & 7;
        tok_lds[b * 9 + t] = (t == 0) ? 5 : tgt[(size_t)(row0 + b) * 8 + t - 1];
    }
    if (tid < 256) bhn_lds[tid] = b_hh[512 + tid];
    for (int i = tid; i < 5 * 256; i += 512) wout_lds[(i >> 8) * 260 + (i & 255)] = Wout[i];
#pragma unroll
    for (int tok = 0; tok < 6; ++tok)
        for (int i = tid; i < 768; i += 512) gtab_lds[tok * 772 + i] = Gtab[tok * 768 + i];
    float bo = (tid < 320) ? bout[tid % 5] : 0.f;

    // ---- init h in LDS buf 0 (bf16) ----
#pragma unroll
    for (int nt = 0; nt < 2; ++nt) {
        int grow = row0 + nt * 32 + bn;
#pragma unroll
        for (int q = 0; q < 4; ++q) {
            int cb = w * 32 + q * 8 + hk * 4;   // gate-col base
            float4 hv = *(const float4*)(latent + (size_t)grow * 256 + cb);
            bf16x4 hb;
            hb[0] = (__bf16)hv.x; hb[1] = (__bf16)hv.y;
            hb[2] = (__bf16)hv.z; hb[3] = (__bf16)hv.w;
            *(bf16x4*)&h_lds[0][nt][2 * w + (q >> 1)][(q & 1) * 32 + bn][4 * hk] = hb;
        }
    }
    __syncthreads();

    for (int t = 0; t < 8; ++t) {
        const int cur = t & 1, nxt = cur ^ 1;
        // ---- MFMA phase: acc[g][nt] += Wfrag(g,kc) * hfrag(nt,kc) ----
        f32x16 acc[3][2];
        {
            f32x16 zz;
#pragma unroll
            for (int i = 0; i < 16; ++i) zz[i] = 0.f;
#pragma unroll
            for (int g = 0; g < 3; ++g)
#pragma unroll
                for (int nt = 0; nt < 2; ++nt) acc[g][nt] = zz;
        }
        // unroll 4: caps in-flight A/B fragments (no spill at 256-reg budget)
#pragma unroll 4
        for (int kc = 0; kc < 16; ++kc) {
            bf16x8 a0 = *(const bf16x8*)(wa + kc * 512);
            bf16x8 a1 = *(const bf16x8*)(wa + 65536 + kc * 512);
            bf16x8 a2 = *(const bf16x8*)(wa + 131072 + kc * 512);
            bf16x8 b0 = *(const bf16x8*)&h_lds[cur][0][kc][lane][0];
            bf16x8 b1 = *(const bf16x8*)&h_lds[cur][1][kc][lane][0];
            acc[0][0] = __builtin_amdgcn_mfma_f32_32x32x16_bf16(a0, b0, acc[0][0], 0, 0, 0);
            acc[0][1] = __builtin_amdgcn_mfma_f32_32x32x16_bf16(a0, b1, acc[0][1], 0, 0, 0);
            acc[1][0] = __builtin_amdgcn_mfma_f32_32x32x16_bf16(a1, b0, acc[1][0], 0, 0, 0);
            acc[1][1] = __builtin_amdgcn_mfma_f32_32x32x16_bf16(a1, b1, acc[1][1], 0, 0, 0);
            acc[2][0] = __builtin_amdgcn_mfma_f32_32x32x16_bf16(a2, b0, acc[2][0], 0, 0, 0);
            acc[2][1] = __builtin_amdgcn_mfma_f32_32x32x16_bf16(a2, b1, acc[2][1], 0, 0, 0);
        }
        // NO barrier: this wave proceeds to combine immediately; h_t goes to
        // the other buffer, so other waves' pending reads of buf[cur] are safe.

        // ---- combine: GRU gate update (lane-local, h_old from buf[cur]) ----
        float p[2][5];
#pragma unroll
        for (int nt = 0; nt < 2; ++nt)
#pragma unroll
            for (int o = 0; o < 5; ++o) p[nt][o] = 0.f;
#pragma unroll
        for (int nt = 0; nt < 2; ++nt) {
            int tok = tok_lds[(nt * 32 + bn) * 9 + t];
            const float* Gt = gtab_lds + tok * 772;
#pragma unroll
            for (int q = 0; q < 4; ++q) {
                int cb = w * 32 + q * 8 + hk * 4;
                float4 g0 = *(const float4*)(Gt + cb);          // i_r + b_ih + b_hh
                float4 g1 = *(const float4*)(Gt + 256 + cb);    // i_z + b_ih + b_hh
                float4 g2 = *(const float4*)(Gt + 512 + cb);    // i_n + b_ih
                float4 bh = *(const float4*)&bhn_lds[cb];       // b_hh (n gate)
                bf16x4 hold = *(const bf16x4*)&h_lds[cur][nt][2 * w + (q >> 1)][(q & 1) * 32 + bn][4 * hk];
                bf16x4 hb;
                float hv[4];
#pragma unroll
                for (int i = 0; i < 4; ++i) {
                    int r = 4 * q + i;
                    float ar = acc[0][nt][r] + f4get(g0, i);
                    float az = acc[1][nt][r] + f4get(g1, i);
                    float hn = acc[2][nt][r] + f4get(bh, i);
                    float rg = sigm(ar);
                    float zg = sigm(az);
                    float ng = tanh_fast(f4get(g2, i) + rg * hn);
                    float hvv = ng + zg * ((float)hold[i] - ng);
                    hv[i] = hvv;
                    hb[i] = (__bf16)hvv;
                }
                *(bf16x4*)&h_lds[nxt][nt][2 * w + (q >> 1)][(q & 1) * 32 + bn][4 * hk] = hb;
                // logit partials from fp32 h values
#pragma unroll
                for (int o = 0; o < 5; ++o) {
                    float4 wv = *(const float4*)&wout_lds[o * 260 + cb];
                    p[nt][o] += wv.x * hv[0] + wv.y * hv[1] + wv.z * hv[2] + wv.w * hv[3];
                }
            }
        }
        // cross-hk reduce within wave, write per-wave partials (dbuf)
#pragma unroll
        for (int nt = 0; nt < 2; ++nt)
#pragma unroll
            for (int o = 0; o < 5; ++o) {
                float v = p[nt][o] + __shfl_xor(p[nt][o], 32, 64);
                if (hk == 0) red[cur][w][nt * 32 + bn][o] = v;
            }
        __syncthreads();   // single barrier: h_lds[nxt] + red[cur] published

        // ---- final reduce across the 8 waves -> logit LDS ----
        if (tid < 320) {
            int b = tid / 5, o = tid - 5 * (tid / 5);
            float sm = bo;
#pragma unroll
            for (int j = 0; j < 8; ++j) sm += red[cur][j][b][o];
            logit_lds[b * 40 + t * 5 + o] = sm;
        }
        // red[nxt] is written next step (after this barrier); red[cur] is not
        // rewritten until step t+2, which is after the t+1 barrier -> race-free.
    }
    __syncthreads();
    // ---- coalesced output dump: 64 rows x (8 t x 5 o) contiguous ----
    for (int i = tid; i < 64 * 40; i += 512)
        out[(size_t)row0 * 40 + i] = logit_lds[i];
}

extern "C" void kernel_launch(void* const* d_in, const int* in_sizes, int n_in,
                              void* d_out, int out_size, void* d_ws, size_t ws_size,
                              hipStream_t stream) {
    const float* latent = (const float*)d_in[0];
    const int*   tgt    = (const int*)d_in[1];
    const float* emb    = (const float*)d_in[2];
    const float* W_ih   = (const float*)d_in[3];
    const float* W_hh   = (const float*)d_in[4];
    const float* b_ih   = (const float*)d_in[5];
    const float* b_hh   = (const float*)d_in[6];
    const float* W_out  = (const float*)d_in[7];
    const float* b_out  = (const float*)d_in[8];
    float* out = (float*)d_out;

    float*  Gtab = (float*)d_ws;                       // 6*768*4   = 18432 B
    __bf16* Wg   = (__bf16*)((char*)d_ws + 18432);     // 768*256*2 = 393216 B

    k_gtable<<<6, 768, 0, stream>>>(emb, W_ih, b_ih, b_hh, Gtab);
    k_wfrag<<<96, 256, 0, stream>>>(W_hh, Wg);
    k_main<<<1024, 512, 0, stream>>>(latent, tgt, Gtab, Wg, b_hh, W_out, b_out, out);
}

// Round 6
// 298.528 us; speedup vs baseline: 3.5005x; 1.1255x over previous
//
#include <hip/hip_runtime.h>
#include <hip/hip_bf16.h>

// AutoregressiveRoutingHead: B=65536, L=8, LATENT=256, HID=128, NTOK=5
//  K1: G[tok][j] = emb[tok]@W_ih[j] + b_ih[j] + (j<512 ? b_hh[j] : 0)   (6x768 f32)
//  K2: W_hh (768x256 f32) -> bf16 fragment-linear for mfma_32x32x16 A-frags
//  K3: 1024 blocks x 512 threads (8 waves, 2/SIMD, 256-reg budget, no spill).
//      Wave w owns gate rows {g*256+32w..+32}; (r,z,n) triples lane-local ->
//      in-register GRU update. h bf16 in LDS, double buffered, 1 barrier/step.
//      NEW (r6): logits computed on the MFMA pipe. W_out is staged zero-padded
//      (5->32 rows) in A-frag layout; waves 0 and 7 each run 16 extra MFMAs/step
//      over the already-resident h B-frags (skewed one step: logits_t need
//      h_{t+1}) and publish directly to logit_lds. Removes per-thread 160 FMA +
//      40 ds_reads + shuffle/reduce tail from the VALU path. tanh = 2*sigm-1.

typedef __attribute__((ext_vector_type(8)))  __bf16 bf16x8;
typedef __attribute__((ext_vector_type(4)))  __bf16 bf16x4;
typedef __attribute__((ext_vector_type(16))) float  f32x16;

__device__ __forceinline__ float sigm(float x) {
    return __builtin_amdgcn_rcpf(1.f + __expf(-x));
}
__device__ __forceinline__ float tanh_fast(float x) {
    // tanh(x) = 2*sigmoid(2x) - 1 ; exact at tails via inf/rcp, 5 VALU ops
    return __builtin_fmaf(2.f, __builtin_amdgcn_rcpf(1.f + __expf(-2.f * x)), -1.f);
}
__device__ __forceinline__ float f4get(const float4& v, int i) {
    return i == 0 ? v.x : i == 1 ? v.y : i == 2 ? v.z : v.w;
}

// ---------------- K1: gi table ----------------
__global__ void k_gtable(const float* __restrict__ emb, const float* __restrict__ W_ih,
                         const float* __restrict__ b_ih, const float* __restrict__ b_hh,
                         float* __restrict__ G) {
    int tok = blockIdx.x;      // 0..5
    int j   = threadIdx.x;     // 0..767
    const float4* e4 = (const float4*)(emb + tok * 128);
    const float4* w4 = (const float4*)(W_ih + (size_t)j * 128);
    float s = 0.f;
#pragma unroll
    for (int k = 0; k < 32; ++k) {
        float4 a = e4[k], b = w4[k];
        s += a.x * b.x + a.y * b.y + a.z * b.z + a.w * b.w;
    }
    s += b_ih[j];
    if (j < 512) s += b_hh[j];   // fold b_hh into r,z gate pre-activations
    G[tok * 768 + j] = s;
}

// ---------------- K2: W_hh -> bf16 fragment-linear ----------------
// Frag (g,w,kc): A[m][k], m = g*256 + 32*w + (lane&31), k = kc*16 + (lane>>5)*8 + j
__global__ void k_wfrag(const float* __restrict__ Whh, __bf16* __restrict__ Wg) {
    int u = blockIdx.x * 256 + threadIdx.x;   // 0..24575
    int lane = u & 63;
    int kc   = (u >> 6) & 15;
    int w    = (u >> 10) & 7;
    int g    = u >> 13;
    int row  = g * 256 + w * 32 + (lane & 31);
    int k0   = kc * 16 + (lane >> 5) * 8;
    const float* src = Whh + (size_t)row * 256 + k0;
    bf16x8 v;
#pragma unroll
    for (int j = 0; j < 8; ++j) v[j] = (__bf16)src[j];
    *(bf16x8*)(Wg + (size_t)u * 8) = v;
}

// ---------------- K3: main recurrent kernel ----------------
__global__ __launch_bounds__(512, 2) void k_main(
    const float* __restrict__ latent, const int* __restrict__ tgt,
    const float* __restrict__ Gtab, const __bf16* __restrict__ Wg,
    const float* __restrict__ b_hh, const float* __restrict__ Wout,
    const float* __restrict__ bout, float* __restrict__ out) {

    __shared__ __bf16 h_lds[2][2][16][64][8]; // [buf][nt][kc][slot][j] : 64 KB
    __shared__ __bf16 woutf_lds[16][64][8];   // W_out A-frags, rows 5..31 = 0 : 16 KB
    __shared__ int    tok_lds[64 * 9];        // padded stride 9
    __shared__ float  gtab_lds[6 * 772];      // Gtab, rows padded +4
    __shared__ float  bhn_lds[256];           // b_hh[512:768]
    __shared__ float  logit_lds[64 * 40];     // accumulated logits (10 KB)

    const int tid  = threadIdx.x;
    const int lane = tid & 63;
    const int w    = tid >> 6;       // wave 0..7 : gate-col slice (cols 32w..+31)
    const int hk   = lane >> 5;      // k-half within frag
    const int bn   = lane & 31;      // batch index within nt-half
    const int row0 = blockIdx.x * 64;

    // per-thread A-frag base: frag(g,kc) at wa + g*65536 + kc*512 (elements)
    const __bf16* wa = Wg + (size_t)w * 8192 + (size_t)lane * 8;

    // ---- stage small tables ----
    {
        int b = tid >> 3, t = tid & 7;
        tok_lds[b * 9 + t] = (t == 0) ? 5 : tgt[(size_t)(row0 + b) * 8 + t - 1];
    }
    if (tid < 256) bhn_lds[tid] = b_hh[512 + tid];
#pragma unroll
    for (int tok = 0; tok < 6; ++tok)
        for (int i = tid; i < 768; i += 512) gtab_lds[tok * 772 + i] = Gtab[tok * 768 + i];
    // W_out A-frags: A[m][k], m=lane&31 (logit o, >=5 zero), k=kc*16+hk*8+j
    for (int kc = w; kc < 16; kc += 8) {
        bf16x8 v;
        if (bn < 5) {
            const float* src = Wout + bn * 256 + kc * 16 + hk * 8;
#pragma unroll
            for (int j = 0; j < 8; ++j) v[j] = (__bf16)src[j];
        } else {
#pragma unroll
            for (int j = 0; j < 8; ++j) v[j] = (__bf16)0.f;
        }
        *(bf16x8*)&woutf_lds[kc][lane][0] = v;
    }
    // logit biases (uniform scalar loads)
    const float bo0 = bout[0], bo1 = bout[1], bo2 = bout[2], bo3 = bout[3], bo4 = bout[4];

    // ---- init h in LDS buf 0 (bf16) ----
#pragma unroll
    for (int nt = 0; nt < 2; ++nt) {
        int grow = row0 + nt * 32 + bn;
#pragma unroll
        for (int q = 0; q < 4; ++q) {
            int cb = w * 32 + q * 8 + hk * 4;   // gate-col base
            float4 hv = *(const float4*)(latent + (size_t)grow * 256 + cb);
            bf16x4 hb;
            hb[0] = (__bf16)hv.x; hb[1] = (__bf16)hv.y;
            hb[2] = (__bf16)hv.z; hb[3] = (__bf16)hv.w;
            *(bf16x4*)&h_lds[0][nt][2 * w + (q >> 1)][(q & 1) * 32 + bn][4 * hk] = hb;
        }
    }
    __syncthreads();

    for (int t = 0; t < 8; ++t) {
        const int cur = t & 1, nxt = cur ^ 1;
        // ---- MFMA phase: acc[g][nt] += Wfrag(g,kc) * hfrag(nt,kc) ----
        f32x16 acc[3][2];
        {
            f32x16 zz;
#pragma unroll
            for (int i = 0; i < 16; ++i) zz[i] = 0.f;
#pragma unroll
            for (int g = 0; g < 3; ++g)
#pragma unroll
                for (int nt = 0; nt < 2; ++nt) acc[g][nt] = zz;
        }
        // unroll 4: caps in-flight A/B fragments (no spill at 256-reg budget)
#pragma unroll 4
        for (int kc = 0; kc < 16; ++kc) {
            bf16x8 a0 = *(const bf16x8*)(wa + kc * 512);
            bf16x8 a1 = *(const bf16x8*)(wa + 65536 + kc * 512);
            bf16x8 a2 = *(const bf16x8*)(wa + 131072 + kc * 512);
            bf16x8 b0 = *(const bf16x8*)&h_lds[cur][0][kc][lane][0];
            bf16x8 b1 = *(const bf16x8*)&h_lds[cur][1][kc][lane][0];
            acc[0][0] = __builtin_amdgcn_mfma_f32_32x32x16_bf16(a0, b0, acc[0][0], 0, 0, 0);
            acc[0][1] = __builtin_amdgcn_mfma_f32_32x32x16_bf16(a0, b1, acc[0][1], 0, 0, 0);
            acc[1][0] = __builtin_amdgcn_mfma_f32_32x32x16_bf16(a1, b0, acc[1][0], 0, 0, 0);
            acc[1][1] = __builtin_amdgcn_mfma_f32_32x32x16_bf16(a1, b1, acc[1][1], 0, 0, 0);
            acc[2][0] = __builtin_amdgcn_mfma_f32_32x32x16_bf16(a2, b0, acc[2][0], 0, 0, 0);
            acc[2][1] = __builtin_amdgcn_mfma_f32_32x32x16_bf16(a2, b1, acc[2][1], 0, 0, 0);
        }

        // ---- logit MFMA (skewed: uses h_t = state BEFORE this step's update,
        //      i.e. the h produced by step t-1 -> logits slot t-1).
        //      Wave 0 handles batch half nt=0, wave 7 handles nt=1. ----
        if ((w == 0 || w == 7) && t > 0) {
            const int nt = (w == 0) ? 0 : 1;
            f32x16 lacc;
#pragma unroll
            for (int i = 0; i < 16; ++i) lacc[i] = 0.f;
#pragma unroll 4
            for (int kc = 0; kc < 16; ++kc) {
                bf16x8 wf = *(const bf16x8*)&woutf_lds[kc][lane][0];
                bf16x8 bb = *(const bf16x8*)&h_lds[cur][nt][kc][lane][0];
                lacc = __builtin_amdgcn_mfma_f32_32x32x16_bf16(wf, bb, lacc, 0, 0, 0);
            }
            // C layout: col(batch)=lane&31, row rr=(reg&3)+8*(reg>>2)+4*hk
            float* dst = &logit_lds[(nt * 32 + bn) * 40 + (t - 1) * 5];
            if (hk == 0) {
                dst[0] = lacc[0] + bo0; dst[1] = lacc[1] + bo1;
                dst[2] = lacc[2] + bo2; dst[3] = lacc[3] + bo3;
            } else {
                dst[4] = lacc[0] + bo4;
            }
        }

        // ---- combine: GRU gate update (lane-local, h_old from buf[cur]) ----
#pragma unroll
        for (int nt = 0; nt < 2; ++nt) {
            int tok = tok_lds[(nt * 32 + bn) * 9 + t];
            const float* Gt = gtab_lds + tok * 772;
#pragma unroll
            for (int q = 0; q < 4; ++q) {
                int cb = w * 32 + q * 8 + hk * 4;
                float4 g0 = *(const float4*)(Gt + cb);          // i_r + b_ih + b_hh
                float4 g1 = *(const float4*)(Gt + 256 + cb);    // i_z + b_ih + b_hh
                float4 g2 = *(const float4*)(Gt + 512 + cb);    // i_n + b_ih
                float4 bh = *(const float4*)&bhn_lds[cb];       // b_hh (n gate)
                bf16x4 hold = *(const bf16x4*)&h_lds[cur][nt][2 * w + (q >> 1)][(q & 1) * 32 + bn][4 * hk];
                bf16x4 hb;
#pragma unroll
                for (int i = 0; i < 4; ++i) {
                    int r = 4 * q + i;
                    float ar = acc[0][nt][r] + f4get(g0, i);
                    float az = acc[1][nt][r] + f4get(g1, i);
                    float hn = acc[2][nt][r] + f4get(bh, i);
                    float rg = sigm(ar);
                    float zg = sigm(az);
                    float ng = tanh_fast(__builtin_fmaf(rg, hn, f4get(g2, i)));
                    float hvv = ng + zg * ((float)hold[i] - ng);
                    hb[i] = (__bf16)hvv;
                }
                *(bf16x4*)&h_lds[nxt][nt][2 * w + (q >> 1)][(q & 1) * 32 + bn][4 * hk] = hb;
            }
        }
        __syncthreads();   // h_lds[nxt] published; logit_lds slot t-1 done
    }

    // ---- epilogue: logits for step 7 from final h (in buf 0 after t=7) ----
    if (w == 0 || w == 7) {
        const int nt = (w == 0) ? 0 : 1;
        f32x16 lacc;
#pragma unroll
        for (int i = 0; i < 16; ++i) lacc[i] = 0.f;
#pragma unroll 4
        for (int kc = 0; kc < 16; ++kc) {
            bf16x8 wf = *(const bf16x8*)&woutf_lds[kc][lane][0];
            bf16x8 bb = *(const bf16x8*)&h_lds[0][nt][kc][lane][0];
            lacc = __builtin_amdgcn_mfma_f32_32x32x16_bf16(wf, bb, lacc, 0, 0, 0);
        }
        float* dst = &logit_lds[(nt * 32 + bn) * 40 + 7 * 5];
        if (hk == 0) {
            dst[0] = lacc[0] + bo0; dst[1] = lacc[1] + bo1;
            dst[2] = lacc[2] + bo2; dst[3] = lacc[3] + bo3;
        } else {
            dst[4] = lacc[0] + bo4;
        }
    }
    __syncthreads();
    // ---- coalesced output dump: 64 rows x (8 t x 5 o) contiguous ----
    for (int i = tid; i < 64 * 40; i += 512)
        out[(size_t)row0 * 40 + i] = logit_lds[i];
}

extern "C" void kernel_launch(void* const* d_in, const int* in_sizes, int n_in,
                              void* d_out, int out_size, void* d_ws, size_t ws_size,
                              hipStream_t stream) {
    const float* latent = (const float*)d_in[0];
    const int*   tgt    = (const int*)d_in[1];
    const float* emb    = (const float*)d_in[2];
    const float* W_ih   = (const float*)d_in[3];
    const float* W_hh   = (const float*)d_in[4];
    const float* b_ih   = (const float*)d_in[5];
    const float* b_hh   = (const float*)d_in[6];
    const float* W_out  = (const float*)d_in[7];
    const float* b_out  = (const float*)d_in[8];
    float* out = (float*)d_out;

    float*  Gtab = (float*)d_ws;                       // 6*768*4   = 18432 B
    __bf16* Wg   = (__bf16*)((char*)d_ws + 18432);     // 768*256*2 = 393216 B

    k_gtable<<<6, 768, 0, stream>>>(emb, W_ih, b_ih, b_hh, Gtab);
    k_wfrag<<<96, 256, 0, stream>>>(W_hh, Wg);
    k_main<<<1024, 512, 0, stream>>>(latent, tgt, Gtab, Wg, b_hh, W_out, b_out, out);
}

// Round 7
// 288.794 us; speedup vs baseline: 3.6184x; 1.0337x over previous
//
#include <hip/hip_runtime.h>
#include <hip/hip_bf16.h>

// AutoregressiveRoutingHead: B=65536, L=8, LATENT=256, HID=128, NTOK=5
//  K1: G[tok][j] = emb[tok]@W_ih[j] + b_ih[j] + (j<512 ? b_hh[j] : 0)  (6x768 f32)
//  K2: augmented W -> bf16 frag-linear Wg2. Per w-slice 52 frags:
//      g in {0,1,2} x kc in 0..16, plus f=51 (g3,kc16).
//      kc<16       : W_hh[g*256+m][kc*16..+16]
//      kc=16, g<2  : one-hot token cols = Gtab[c][g*256+m]  (i_r,i_z + biases)
//      kc=16, g=2  : bhn[m] in every hot col (token-indep bias of n h-part)
//      f=51 (g3)   : Gtab[c][512+m]  (i_n) -- g3 has ONLY kc16
//  K3: 1024 blocks x 512 threads (8 waves, 2/SIMD). MFMA over K=272 yields
//      acc0=r-pre, acc1=z-pre, acc2=Whn.h+bhn, acc3=i_n -> combine is pure
//      VALU + one LDS hold-read. One-hot B-frags precomputed per step at init.
//      kc16 A-frags persistent in regs; kc0-1 A-frags prefetched across a RAW
//      s_barrier (lgkmcnt-only drain) so the L2 W-stream overlaps the combine.
//      h bf16 in LDS, double buffered; logits via MFMA on waves 0/7 (skewed).

typedef __attribute__((ext_vector_type(8)))  __bf16 bf16x8;
typedef __attribute__((ext_vector_type(4)))  __bf16 bf16x4;
typedef __attribute__((ext_vector_type(16))) float  f32x16;

__device__ __forceinline__ float sigm(float x) {
    return __builtin_amdgcn_rcpf(1.f + __expf(-x));
}
__device__ __forceinline__ float tanh_fast(float x) {
    // tanh(x) = 2*sigmoid(2x) - 1
    return __builtin_fmaf(2.f, __builtin_amdgcn_rcpf(1.f + __expf(-2.f * x)), -1.f);
}
__device__ __forceinline__ void lds_barrier() {
    // LDS-only barrier: drains ds ops, NOT vmem -> global prefetches survive.
    __builtin_amdgcn_sched_barrier(0);
    asm volatile("s_waitcnt lgkmcnt(0)" ::: "memory");
    __builtin_amdgcn_s_barrier();
    __builtin_amdgcn_sched_barrier(0);
}

// ---------------- K1: gi table ----------------
__global__ void k_gtable(const float* __restrict__ emb, const float* __restrict__ W_ih,
                         const float* __restrict__ b_ih, const float* __restrict__ b_hh,
                         float* __restrict__ G) {
    int tok = blockIdx.x;      // 0..5
    int j   = threadIdx.x;     // 0..767
    const float4* e4 = (const float4*)(emb + tok * 128);
    const float4* w4 = (const float4*)(W_ih + (size_t)j * 128);
    float s = 0.f;
#pragma unroll
    for (int k = 0; k < 32; ++k) {
        float4 a = e4[k], b = w4[k];
        s += a.x * b.x + a.y * b.y + a.z * b.z + a.w * b.w;
    }
    s += b_ih[j];
    if (j < 512) s += b_hh[j];   // fold b_hh into r,z gate pre-activations
    G[tok * 768 + j] = s;
}

// ---------------- K2: augmented W -> bf16 fragment-linear ----------------
__global__ void k_wfrag2(const float* __restrict__ Whh, const float* __restrict__ Gtab,
                         const float* __restrict__ b_hh, __bf16* __restrict__ Wg) {
    int u    = blockIdx.x * 256 + threadIdx.x;   // 0..26623 (416 frags x 64 lanes)
    int lane = u & 63;
    int frag = u >> 6;           // 0..415
    int w    = frag / 52;
    int f    = frag - 52 * w;    // 0..51
    int m    = w * 32 + (lane & 31);
    int cb   = (lane >> 5) * 8;
    bf16x8 v;
    if (f == 51) {               // g3 kc16: i_n one-hot columns
#pragma unroll
        for (int j = 0; j < 8; ++j) {
            int c = cb + j;
            v[j] = (c < 6) ? (__bf16)Gtab[c * 768 + 512 + m] : (__bf16)0.f;
        }
    } else {
        int g = f / 17, kc = f - 17 * g;
        if (kc < 16) {
            const float* src = Whh + (size_t)(g * 256 + m) * 256 + kc * 16 + cb;
#pragma unroll
            for (int j = 0; j < 8; ++j) v[j] = (__bf16)src[j];
        } else {                 // kc==16: one-hot columns for gate g
#pragma unroll
            for (int j = 0; j < 8; ++j) {
                int c = cb + j;
                float val = 0.f;
                if (c < 6) val = (g < 2) ? Gtab[c * 768 + g * 256 + m] : b_hh[512 + m];
                v[j] = (__bf16)val;
            }
        }
    }
    *(bf16x8*)(Wg + (size_t)u * 8) = v;
}

// ---------------- K3: main recurrent kernel ----------------
__global__ __launch_bounds__(512, 2) void k_main(
    const float* __restrict__ latent, const int* __restrict__ tgt,
    const __bf16* __restrict__ Wg, const float* __restrict__ Wout,
    const float* __restrict__ bout, float* __restrict__ out) {

    __shared__ __bf16 h_lds[2][2][16][64][8];   // [buf][nt][kc][slot][j] : 64 KB
    __shared__ __bf16 onehot_lds[8][2][64][8];  // per-step one-hot B-frags : 16 KB
    __shared__ __bf16 woutf_lds[16][64][8];     // W_out A-frags (rows 5..31 = 0)
    __shared__ float  logit_lds[64 * 40];       // logits (10 KB)

    const int tid  = threadIdx.x;
    const int lane = tid & 63;
    const int w    = tid >> 6;       // wave 0..7 : gate-col slice (cols 32w..+31)
    const int hk   = lane >> 5;      // k-half within frag
    const int bn   = lane & 31;      // batch index within nt-half
    const int row0 = blockIdx.x * 64;

    // per-thread A-frag base; frag f at wbase + f*512 elements
    const __bf16* wbase = Wg + ((size_t)(w * 52) * 64 + lane) * 8;

    // persistent kc16 A-frags (step-invariant) + kc0/kc1 prefetch
    bf16x8 A16_0 = *(const bf16x8*)(wbase + 16 * 512);
    bf16x8 A16_1 = *(const bf16x8*)(wbase + 33 * 512);
    bf16x8 A16_2 = *(const bf16x8*)(wbase + 50 * 512);
    bf16x8 A16_3 = *(const bf16x8*)(wbase + 51 * 512);
    bf16x8 p0a = *(const bf16x8*)(wbase + 0 * 512);
    bf16x8 p0b = *(const bf16x8*)(wbase + 17 * 512);
    bf16x8 p0c = *(const bf16x8*)(wbase + 34 * 512);
    bf16x8 p1a = *(const bf16x8*)(wbase + 1 * 512);
    bf16x8 p1b = *(const bf16x8*)(wbase + 18 * 512);
    bf16x8 p1c = *(const bf16x8*)(wbase + 35 * 512);

    // ---- one-hot B-frags for all 8 steps ----
    for (int r = tid; r < 1024; r += 512) {
        int t = r >> 7, nt = (r >> 6) & 1, ln = r & 63;
        int brow = row0 + nt * 32 + (ln & 31);
        int tok = (t == 0) ? 5 : tgt[(size_t)brow * 8 + t - 1];
        int cbase = (ln >> 5) * 8;
        bf16x8 v;
#pragma unroll
        for (int j = 0; j < 8; ++j) v[j] = (__bf16)((cbase + j == tok) ? 1.f : 0.f);
        *(bf16x8*)&onehot_lds[t][nt][ln][0] = v;
    }
    // ---- W_out A-frags ----
    for (int kc = w; kc < 16; kc += 8) {
        bf16x8 v;
        if (bn < 5) {
            const float* src = Wout + bn * 256 + kc * 16 + hk * 8;
#pragma unroll
            for (int j = 0; j < 8; ++j) v[j] = (__bf16)src[j];
        } else {
#pragma unroll
            for (int j = 0; j < 8; ++j) v[j] = (__bf16)0.f;
        }
        *(bf16x8*)&woutf_lds[kc][lane][0] = v;
    }
    const float bo0 = bout[0], bo1 = bout[1], bo2 = bout[2], bo3 = bout[3], bo4 = bout[4];

    // ---- init h in LDS buf 0 (bf16) ----
#pragma unroll
    for (int nt = 0; nt < 2; ++nt) {
        int grow = row0 + nt * 32 + bn;
#pragma unroll
        for (int q = 0; q < 4; ++q) {
            int cb = w * 32 + q * 8 + hk * 4;
            float4 hv = *(const float4*)(latent + (size_t)grow * 256 + cb);
            bf16x4 hb;
            hb[0] = (__bf16)hv.x; hb[1] = (__bf16)hv.y;
            hb[2] = (__bf16)hv.z; hb[3] = (__bf16)hv.w;
            *(bf16x4*)&h_lds[0][nt][2 * w + (q >> 1)][(q & 1) * 32 + bn][4 * hk] = hb;
        }
    }
    __syncthreads();

    for (int t = 0; t < 8; ++t) {
        const int cur = t & 1, nxt = cur ^ 1;
        f32x16 acc[4][2];
        {
            f32x16 zz;
#pragma unroll
            for (int i = 0; i < 16; ++i) zz[i] = 0.f;
#pragma unroll
            for (int g = 0; g < 4; ++g)
#pragma unroll
                for (int nt = 0; nt < 2; ++nt) acc[g][nt] = zz;
        }
        // ---- kc16 (one-hot columns): operands resident ----
        {
            bf16x8 oh0 = *(const bf16x8*)&onehot_lds[t][0][lane][0];
            bf16x8 oh1 = *(const bf16x8*)&onehot_lds[t][1][lane][0];
            acc[0][0] = __builtin_amdgcn_mfma_f32_32x32x16_bf16(A16_0, oh0, acc[0][0], 0, 0, 0);
            acc[0][1] = __builtin_amdgcn_mfma_f32_32x32x16_bf16(A16_0, oh1, acc[0][1], 0, 0, 0);
            acc[1][0] = __builtin_amdgcn_mfma_f32_32x32x16_bf16(A16_1, oh0, acc[1][0], 0, 0, 0);
            acc[1][1] = __builtin_amdgcn_mfma_f32_32x32x16_bf16(A16_1, oh1, acc[1][1], 0, 0, 0);
            acc[2][0] = __builtin_amdgcn_mfma_f32_32x32x16_bf16(A16_2, oh0, acc[2][0], 0, 0, 0);
            acc[2][1] = __builtin_amdgcn_mfma_f32_32x32x16_bf16(A16_2, oh1, acc[2][1], 0, 0, 0);
            acc[3][0] = __builtin_amdgcn_mfma_f32_32x32x16_bf16(A16_3, oh0, acc[3][0], 0, 0, 0);
            acc[3][1] = __builtin_amdgcn_mfma_f32_32x32x16_bf16(A16_3, oh1, acc[3][1], 0, 0, 0);
        }
        // ---- kc0, kc1 from prefetch regs ----
        {
            bf16x8 b0 = *(const bf16x8*)&h_lds[cur][0][0][lane][0];
            bf16x8 b1 = *(const bf16x8*)&h_lds[cur][1][0][lane][0];
            acc[0][0] = __builtin_amdgcn_mfma_f32_32x32x16_bf16(p0a, b0, acc[0][0], 0, 0, 0);
            acc[0][1] = __builtin_amdgcn_mfma_f32_32x32x16_bf16(p0a, b1, acc[0][1], 0, 0, 0);
            acc[1][0] = __builtin_amdgcn_mfma_f32_32x32x16_bf16(p0b, b0, acc[1][0], 0, 0, 0);
            acc[1][1] = __builtin_amdgcn_mfma_f32_32x32x16_bf16(p0b, b1, acc[1][1], 0, 0, 0);
            acc[2][0] = __builtin_amdgcn_mfma_f32_32x32x16_bf16(p0c, b0, acc[2][0], 0, 0, 0);
            acc[2][1] = __builtin_amdgcn_mfma_f32_32x32x16_bf16(p0c, b1, acc[2][1], 0, 0, 0);
            b0 = *(const bf16x8*)&h_lds[cur][0][1][lane][0];
            b1 = *(const bf16x8*)&h_lds[cur][1][1][lane][0];
            acc[0][0] = __builtin_amdgcn_mfma_f32_32x32x16_bf16(p1a, b0, acc[0][0], 0, 0, 0);
            acc[0][1] = __builtin_amdgcn_mfma_f32_32x32x16_bf16(p1a, b1, acc[0][1], 0, 0, 0);
            acc[1][0] = __builtin_amdgcn_mfma_f32_32x32x16_bf16(p1b, b0, acc[1][0], 0, 0, 0);
            acc[1][1] = __builtin_amdgcn_mfma_f32_32x32x16_bf16(p1b, b1, acc[1][1], 0, 0, 0);
            acc[2][0] = __builtin_amdgcn_mfma_f32_32x32x16_bf16(p1c, b0, acc[2][0], 0, 0, 0);
            acc[2][1] = __builtin_amdgcn_mfma_f32_32x32x16_bf16(p1c, b1, acc[2][1], 0, 0, 0);
        }
        // ---- stream kc 2..15 from L2 ----
#pragma unroll 2
        for (int kc = 2; kc < 16; ++kc) {
            bf16x8 a0 = *(const bf16x8*)(wbase + kc * 512);
            bf16x8 a1 = *(const bf16x8*)(wbase + (17 + kc) * 512);
            bf16x8 a2 = *(const bf16x8*)(wbase + (34 + kc) * 512);
            bf16x8 b0 = *(const bf16x8*)&h_lds[cur][0][kc][lane][0];
            bf16x8 b1 = *(const bf16x8*)&h_lds[cur][1][kc][lane][0];
            acc[0][0] = __builtin_amdgcn_mfma_f32_32x32x16_bf16(a0, b0, acc[0][0], 0, 0, 0);
            acc[0][1] = __builtin_amdgcn_mfma_f32_32x32x16_bf16(a0, b1, acc[0][1], 0, 0, 0);
            acc[1][0] = __builtin_amdgcn_mfma_f32_32x32x16_bf16(a1, b0, acc[1][0], 0, 0, 0);
            acc[1][1] = __builtin_amdgcn_mfma_f32_32x32x16_bf16(a1, b1, acc[1][1], 0, 0, 0);
            acc[2][0] = __builtin_amdgcn_mfma_f32_32x32x16_bf16(a2, b0, acc[2][0], 0, 0, 0);
            acc[2][1] = __builtin_amdgcn_mfma_f32_32x32x16_bf16(a2, b1, acc[2][1], 0, 0, 0);
        }
        // ---- re-issue kc0/kc1 prefetch for next step (survives raw barrier) ----
        p0a = *(const bf16x8*)(wbase + 0 * 512);
        p0b = *(const bf16x8*)(wbase + 17 * 512);
        p0c = *(const bf16x8*)(wbase + 34 * 512);
        p1a = *(const bf16x8*)(wbase + 1 * 512);
        p1b = *(const bf16x8*)(wbase + 18 * 512);
        p1c = *(const bf16x8*)(wbase + 35 * 512);

        // ---- logit MFMA (skewed by one step), waves 0 and 7 ----
        if ((w == 0 || w == 7) && t > 0) {
            const int nt = (w == 0) ? 0 : 1;
            f32x16 lacc;
#pragma unroll
            for (int i = 0; i < 16; ++i) lacc[i] = 0.f;
#pragma unroll 4
            for (int kc = 0; kc < 16; ++kc) {
                bf16x8 wf = *(const bf16x8*)&woutf_lds[kc][lane][0];
                bf16x8 bb = *(const bf16x8*)&h_lds[cur][nt][kc][lane][0];
                lacc = __builtin_amdgcn_mfma_f32_32x32x16_bf16(wf, bb, lacc, 0, 0, 0);
            }
            float* dst = &logit_lds[(nt * 32 + bn) * 40 + (t - 1) * 5];
            if (hk == 0) {
                dst[0] = lacc[0] + bo0; dst[1] = lacc[1] + bo1;
                dst[2] = lacc[2] + bo2; dst[3] = lacc[3] + bo3;
            } else {
                dst[4] = lacc[0] + bo4;
            }
        }

        // ---- combine: pure-VALU GRU update (acc0..3 are bias-complete) ----
#pragma unroll
        for (int nt = 0; nt < 2; ++nt) {
#pragma unroll
            for (int q = 0; q < 4; ++q) {
                bf16x4 hold = *(const bf16x4*)&h_lds[cur][nt][2 * w + (q >> 1)][(q & 1) * 32 + bn][4 * hk];
                bf16x4 hb;
#pragma unroll
                for (int i = 0; i < 4; ++i) {
                    int r = 4 * q + i;
                    float rg = sigm(acc[0][nt][r]);
                    float zg = sigm(acc[1][nt][r]);
                    float ng = tanh_fast(__builtin_fmaf(rg, acc[2][nt][r], acc[3][nt][r]));
                    float hv = ng + zg * ((float)hold[i] - ng);
                    hb[i] = (__bf16)hv;
                }
                *(bf16x4*)&h_lds[nxt][nt][2 * w + (q >> 1)][(q & 1) * 32 + bn][4 * hk] = hb;
            }
        }
        lds_barrier();   // LDS-only: h_lds[nxt] published, vmem prefetch in flight
    }

    // ---- epilogue: logits for step 7 from final h (buf 0 after t=7) ----
    if (w == 0 || w == 7) {
        const int nt = (w == 0) ? 0 : 1;
        f32x16 lacc;
#pragma unroll
        for (int i = 0; i < 16; ++i) lacc[i] = 0.f;
#pragma unroll 4
        for (int kc = 0; kc < 16; ++kc) {
            bf16x8 wf = *(const bf16x8*)&woutf_lds[kc][lane][0];
            bf16x8 bb = *(const bf16x8*)&h_lds[0][nt][kc][lane][0];
            lacc = __builtin_amdgcn_mfma_f32_32x32x16_bf16(wf, bb, lacc, 0, 0, 0);
        }
        float* dst = &logit_lds[(nt * 32 + bn) * 40 + 7 * 5];
        if (hk == 0) {
            dst[0] = lacc[0] + bo0; dst[1] = lacc[1] + bo1;
            dst[2] = lacc[2] + bo2; dst[3] = lacc[3] + bo3;
        } else {
            dst[4] = lacc[0] + bo4;
        }
    }
    __syncthreads();
    // ---- coalesced output dump ----
    for (int i = tid; i < 64 * 40; i += 512)
        out[(size_t)row0 * 40 + i] = logit_lds[i];
}

extern "C" void kernel_launch(void* const* d_in, const int* in_sizes, int n_in,
                              void* d_out, int out_size, void* d_ws, size_t ws_size,
                              hipStream_t stream) {
    const float* latent = (const float*)d_in[0];
    const int*   tgt    = (const int*)d_in[1];
    const float* emb    = (const float*)d_in[2];
    const float* W_ih   = (const float*)d_in[3];
    const float* W_hh   = (const float*)d_in[4];
    const float* b_ih   = (const float*)d_in[5];
    const float* b_hh   = (const float*)d_in[6];
    const float* W_out  = (const float*)d_in[7];
    const float* b_out  = (const float*)d_in[8];
    float* out = (float*)d_out;

    float*  Gtab = (float*)d_ws;                       // 6*768*4 = 18432 B
    __bf16* Wg2  = (__bf16*)((char*)d_ws + 18432);     // 416 frags*512*2 = 425984 B

    k_gtable<<<6, 768, 0, stream>>>(emb, W_ih, b_ih, b_hh, Gtab);
    k_wfrag2<<<104, 256, 0, stream>>>(W_hh, Gtab, b_hh, Wg2);
    k_main<<<1024, 512, 0, stream>>>(latent, tgt, Wg2, W_out, b_out, out);
}

// Round 8
// 265.054 us; speedup vs baseline: 3.9425x; 1.0896x over previous
//
#include <hip/hip_runtime.h>
#include <hip/hip_bf16.h>

// AutoregressiveRoutingHead: B=65536, L=8, LATENT=256, HID=128, NTOK=5
//  K1: G[tok][j] = emb[tok]@W_ih[j] + b_ih[j] + (j<512 ? b_hh[j] : 0)  (6x768 f32)
//  K2: augmented W -> bf16 frag-linear Wg for mfma_f32_16x16x32_bf16.
//      Per wave-slice w (cols 16w..16w+15), 28 frags of 16x32:
//        f = g*8+kc (g<3, kc<8): W_hh[g*256+col][kc*32..+32]
//        f = 24+g: one-hot K-block (k<6 hot): g0/g1 = Gtab r/z cols,
//                  g2 = bhn (any tok), g3 = Gtab i_n cols
//  K3: 1024 blocks x 1024 threads (16 waves -> 4 waves/SIMD, 128-reg cap).
//      Wave w owns gate-cols [16w,16w+16) for r,z,n,i_n across ALL 4 N-tiles
//      (64 batch rows) -> acc[4][4] f32x4 = 64 regs; each A-frag loaded by
//      exactly one wave (L2 stream unchanged). MFMA over K=288 yields
//      bias-complete gates; combine = pure VALU + one b64 hold-read.
//      h bf16 in LDS, double-buffered, ONE lds_barrier per step. Logits via
//      MFMA on waves 0/5/10/15 (one per SIMD), skewed one step.

typedef __attribute__((ext_vector_type(8)))  __bf16 bf16x8;
typedef __attribute__((ext_vector_type(4)))  __bf16 bf16x4;
typedef __attribute__((ext_vector_type(4)))  float  f32x4;

__device__ __forceinline__ float sigm(float x) {
    return __builtin_amdgcn_rcpf(1.f + __expf(-x));
}
__device__ __forceinline__ float tanh_fast(float x) {
    // tanh(x) = 2*sigmoid(2x) - 1
    return __builtin_fmaf(2.f, __builtin_amdgcn_rcpf(1.f + __expf(-2.f * x)), -1.f);
}
__device__ __forceinline__ void lds_barrier() {
    // LDS-only barrier: drains ds ops, NOT vmem -> global prefetches survive.
    __builtin_amdgcn_sched_barrier(0);
    asm volatile("s_waitcnt lgkmcnt(0)" ::: "memory");
    __builtin_amdgcn_s_barrier();
    __builtin_amdgcn_sched_barrier(0);
}

// ---------------- K1: gi table ----------------
__global__ void k_gtable(const float* __restrict__ emb, const float* __restrict__ W_ih,
                         const float* __restrict__ b_ih, const float* __restrict__ b_hh,
                         float* __restrict__ G) {
    int tok = blockIdx.x;      // 0..5
    int j   = threadIdx.x;     // 0..767
    const float4* e4 = (const float4*)(emb + tok * 128);
    const float4* w4 = (const float4*)(W_ih + (size_t)j * 128);
    float s = 0.f;
#pragma unroll
    for (int k = 0; k < 32; ++k) {
        float4 a = e4[k], b = w4[k];
        s += a.x * b.x + a.y * b.y + a.z * b.z + a.w * b.w;
    }
    s += b_ih[j];
    if (j < 512) s += b_hh[j];   // fold b_hh into r,z gate pre-activations
    G[tok * 768 + j] = s;
}

// ---------------- K2: augmented W -> 16x16x32 A-frags ----------------
// Frag layout: lane = m + 16*kq (m=0..15, kq=0..3), elem j -> k = kq*8+j.
__global__ void k_wfrag3(const float* __restrict__ Whh, const float* __restrict__ Gtab,
                         const float* __restrict__ b_hh, __bf16* __restrict__ Wg) {
    int u    = blockIdx.x * 256 + threadIdx.x;   // 0..28671 (448 frags x 64 lanes)
    int lane = u & 63;
    int frag = u >> 6;            // 0..447
    int w    = frag / 28;
    int f    = frag - 28 * w;     // 0..27
    int col  = w * 16 + (lane & 15);
    int kq   = lane >> 4;
    bf16x8 v;
    if (f < 24) {
        int g = f >> 3, kc = f & 7;
        const float* src = Whh + (size_t)(g * 256 + col) * 256 + kc * 32 + kq * 8;
#pragma unroll
        for (int j = 0; j < 8; ++j) v[j] = (__bf16)src[j];
    } else {
        int g = f - 24;
#pragma unroll
        for (int j = 0; j < 8; ++j) {
            int k = kq * 8 + j;
            float val = 0.f;
            if (k < 6) {
                val = (g == 0) ? Gtab[k * 768 + col]
                    : (g == 1) ? Gtab[k * 768 + 256 + col]
                    : (g == 2) ? b_hh[512 + col]
                               : Gtab[k * 768 + 512 + col];
            }
            v[j] = (__bf16)val;
        }
    }
    *(bf16x8*)(Wg + (size_t)u * 8) = v;
}

// ---------------- K3: main recurrent kernel ----------------
__global__ __launch_bounds__(1024) void k_main(
    const float* __restrict__ latent, const int* __restrict__ tgt,
    const __bf16* __restrict__ Wg, const float* __restrict__ Wout,
    const float* __restrict__ bout, float* __restrict__ out) {

    __shared__ __bf16 h_lds[2][4][8][64][8];    // [buf][nt][kc][lane][j] : 64 KB
    __shared__ __bf16 onehot_lds[8][4][64][8];  // per-step one-hot B-frags : 32 KB
    __shared__ __bf16 woutf_lds[8][64][8];      // W_out A-frags (rows 5..15 = 0) : 8 KB
    __shared__ float  logit_lds[64 * 40];       // logits (10 KB)

    const int tid  = threadIdx.x;
    const int lane = tid & 63;
    const int w    = tid >> 6;       // wave 0..15 : gate-col slice [16w,16w+16)
    const int q    = lane >> 4;      // k-quad within frag / row-quad in C
    const int n16  = lane & 15;      // batch index within 16-row N-tile
    const int row0 = blockIdx.x * 64;

    // per-thread A-frag base; local frag f at wbase + f*512 elements
    const __bf16* wbase = Wg + ((size_t)(w * 28) * 64 + lane) * 8;

    // h/hold LDS address components (combine-element <-> B-frag mapping):
    // element (nt, col=16w+4q+i): kc_h=w>>1, lane'=n16+16*((2w+(q>>1))&3), j=4*(q&1)+i
    const int kc_h  = w >> 1;
    const int slotl = n16 + 16 * ((2 * w + (q >> 1)) & 3);
    const int joff  = 4 * (q & 1);

    // ---- stage W_out A-frags (16 rows, 5 used) ----
    if (tid < 512) {
        int kc = tid >> 6, ln = tid & 63, m = ln & 15, kq2 = ln >> 4;
        bf16x8 v;
#pragma unroll
        for (int j = 0; j < 8; ++j)
            v[j] = (m < 5) ? (__bf16)Wout[m * 256 + kc * 32 + kq2 * 8 + j] : (__bf16)0.f;
        *(bf16x8*)&woutf_lds[kc][ln][0] = v;
    }
    // ---- one-hot B-frags for all 8 steps ----
    for (int s = tid; s < 2048; s += 1024) {
        int t = s >> 8, nt = (s >> 6) & 3, ln = s & 63;
        int nn = ln & 15, kq2 = ln >> 4;
        int tok = (t == 0) ? 5 : tgt[(size_t)(row0 + nt * 16 + nn) * 8 + t - 1];
        bf16x8 v;
#pragma unroll
        for (int j = 0; j < 8; ++j) v[j] = (__bf16)((kq2 * 8 + j == tok) ? 1.f : 0.f);
        *(bf16x8*)&onehot_lds[t][nt][ln][0] = v;
    }
    // ---- init h in LDS buf 0 (bf16), same mapping as combine-write ----
#pragma unroll
    for (int nt = 0; nt < 4; ++nt) {
        float4 hv = *(const float4*)(latent + (size_t)(row0 + nt * 16 + n16) * 256 + 16 * w + 4 * q);
        bf16x4 hb;
        hb[0] = (__bf16)hv.x; hb[1] = (__bf16)hv.y;
        hb[2] = (__bf16)hv.z; hb[3] = (__bf16)hv.w;
        *(bf16x4*)&h_lds[0][nt][kc_h][slotl][joff] = hb;
    }
    // logit-wave assignment: one per SIMD (waves 0,5,10,15 -> nt 0..3)
    const int lw = (w == 0) ? 0 : (w == 5) ? 1 : (w == 10) ? 2 : (w == 15) ? 3 : -1;
    const float bo0 = bout[0], bo1 = bout[1], bo2 = bout[2], bo3 = bout[3], bo4 = bout[4];
    __syncthreads();

    for (int t = 0; t < 8; ++t) {
        const int cur = t & 1, nxt = cur ^ 1;
        f32x4 acc[4][4];   // [gate][nt]
#pragma unroll
        for (int g = 0; g < 4; ++g)
#pragma unroll
            for (int nt = 0; nt < 4; ++nt)
#pragma unroll
                for (int i = 0; i < 4; ++i) acc[g][nt][i] = 0.f;

        // ---- stream kc 0..7 from L2 (each frag loaded by exactly one wave) ----
#pragma unroll 2
        for (int kc = 0; kc < 8; ++kc) {
            bf16x8 a0 = *(const bf16x8*)(wbase + (size_t)kc * 512);
            bf16x8 a1 = *(const bf16x8*)(wbase + (size_t)(8 + kc) * 512);
            bf16x8 a2 = *(const bf16x8*)(wbase + (size_t)(16 + kc) * 512);
#pragma unroll
            for (int nt = 0; nt < 4; ++nt) {
                bf16x8 bb = *(const bf16x8*)&h_lds[cur][nt][kc][lane][0];
                acc[0][nt] = __builtin_amdgcn_mfma_f32_16x16x32_bf16(a0, bb, acc[0][nt], 0, 0, 0);
                acc[1][nt] = __builtin_amdgcn_mfma_f32_16x16x32_bf16(a1, bb, acc[1][nt], 0, 0, 0);
                acc[2][nt] = __builtin_amdgcn_mfma_f32_16x16x32_bf16(a2, bb, acc[2][nt], 0, 0, 0);
            }
        }
        // ---- one-hot K-block (delivers i_r,i_z,bhn,i_n into the accs) ----
        {
            bf16x8 a0 = *(const bf16x8*)(wbase + (size_t)24 * 512);
            bf16x8 a1 = *(const bf16x8*)(wbase + (size_t)25 * 512);
            bf16x8 a2 = *(const bf16x8*)(wbase + (size_t)26 * 512);
            bf16x8 a3 = *(const bf16x8*)(wbase + (size_t)27 * 512);
#pragma unroll
            for (int nt = 0; nt < 4; ++nt) {
                bf16x8 oh = *(const bf16x8*)&onehot_lds[t][nt][lane][0];
                acc[0][nt] = __builtin_amdgcn_mfma_f32_16x16x32_bf16(a0, oh, acc[0][nt], 0, 0, 0);
                acc[1][nt] = __builtin_amdgcn_mfma_f32_16x16x32_bf16(a1, oh, acc[1][nt], 0, 0, 0);
                acc[2][nt] = __builtin_amdgcn_mfma_f32_16x16x32_bf16(a2, oh, acc[2][nt], 0, 0, 0);
                acc[3][nt] = __builtin_amdgcn_mfma_f32_16x16x32_bf16(a3, oh, acc[3][nt], 0, 0, 0);
            }
        }

        // ---- logit MFMA (skewed one step), one wave per SIMD ----
        if (lw >= 0 && t > 0) {
            f32x4 lacc;
#pragma unroll
            for (int i = 0; i < 4; ++i) lacc[i] = 0.f;
#pragma unroll
            for (int kc = 0; kc < 8; ++kc) {
                bf16x8 wf = *(const bf16x8*)&woutf_lds[kc][lane][0];
                bf16x8 bb = *(const bf16x8*)&h_lds[cur][lw][kc][lane][0];
                lacc = __builtin_amdgcn_mfma_f32_16x16x32_bf16(wf, bb, lacc, 0, 0, 0);
            }
            // C: batch = lane&15, o = q*4 + i
            float* dst = &logit_lds[(lw * 16 + n16) * 40 + (t - 1) * 5];
            if (q == 0) {
                dst[0] = lacc[0] + bo0; dst[1] = lacc[1] + bo1;
                dst[2] = lacc[2] + bo2; dst[3] = lacc[3] + bo3;
            } else if (q == 1) {
                dst[4] = lacc[0] + bo4;
            }
        }

        // ---- combine: pure-VALU GRU update (accs bias-complete) ----
#pragma unroll
        for (int nt = 0; nt < 4; ++nt) {
            bf16x4 hold = *(const bf16x4*)&h_lds[cur][nt][kc_h][slotl][joff];
            bf16x4 hb;
#pragma unroll
            for (int i = 0; i < 4; ++i) {
                float rg = sigm(acc[0][nt][i]);
                float zg = sigm(acc[1][nt][i]);
                float ng = tanh_fast(__builtin_fmaf(rg, acc[2][nt][i], acc[3][nt][i]));
                float hv = ng + zg * ((float)hold[i] - ng);
                hb[i] = (__bf16)hv;
            }
            *(bf16x4*)&h_lds[nxt][nt][kc_h][slotl][joff] = hb;
        }
        lds_barrier();   // h_lds[nxt] published; one barrier per step
    }

    // ---- epilogue: logits for step 7 from final h (buf 0 after t=7) ----
    if (lw >= 0) {
        f32x4 lacc;
#pragma unroll
        for (int i = 0; i < 4; ++i) lacc[i] = 0.f;
#pragma unroll
        for (int kc = 0; kc < 8; ++kc) {
            bf16x8 wf = *(const bf16x8*)&woutf_lds[kc][lane][0];
            bf16x8 bb = *(const bf16x8*)&h_lds[0][lw][kc][lane][0];
            lacc = __builtin_amdgcn_mfma_f32_16x16x32_bf16(wf, bb, lacc, 0, 0, 0);
        }
        float* dst = &logit_lds[(lw * 16 + n16) * 40 + 7 * 5];
        if (q == 0) {
            dst[0] = lacc[0] + bo0; dst[1] = lacc[1] + bo1;
            dst[2] = lacc[2] + bo2; dst[3] = lacc[3] + bo3;
        } else if (q == 1) {
            dst[4] = lacc[0] + bo4;
        }
    }
    __syncthreads();
    // ---- coalesced output dump: 64 rows x (8 t x 5 o) contiguous ----
    for (int i = tid; i < 64 * 40; i += 1024)
        out[(size_t)row0 * 40 + i] = logit_lds[i];
}

extern "C" void kernel_launch(void* const* d_in, const int* in_sizes, int n_in,
                              void* d_out, int out_size, void* d_ws, size_t ws_size,
                              hipStream_t stream) {
    const float* latent = (const float*)d_in[0];
    const int*   tgt    = (const int*)d_in[1];
    const float* emb    = (const float*)d_in[2];
    const float* W_ih   = (const float*)d_in[3];
    const float* W_hh   = (const float*)d_in[4];
    const float* b_ih   = (const float*)d_in[5];
    const float* b_hh   = (const float*)d_in[6];
    const float* W_out  = (const float*)d_in[7];
    const float* b_out  = (const float*)d_in[8];
    float* out = (float*)d_out;

    float*  Gtab = (float*)d_ws;                       // 6*768*4 = 18432 B
    __bf16* Wg   = (__bf16*)((char*)d_ws + 18432);     // 448 frags*512*2 = 458752 B

    k_gtable<<<6, 768, 0, stream>>>(emb, W_ih, b_ih, b_hh, Gtab);
    k_wfrag3<<<112, 256, 0, stream>>>(W_hh, Gtab, b_hh, Wg);
    k_main<<<1024, 1024, 0, stream>>>(latent, tgt, Wg, W_out, b_out, out);
}